// Round 1
// baseline (271.346 us; speedup 1.0000x reference)
//
#include <hip/hip_runtime.h>
#include <cstdint>

using u16 = unsigned short;
using u32 = unsigned int;

typedef __attribute__((ext_vector_type(8))) short short8;   // 8 bf16 (A/B frag)
typedef __attribute__((ext_vector_type(4))) float floatx4;  // C frag

__device__ __forceinline__ u16 f2bf(float f) {
    u32 u = __float_as_uint(f);
    u32 r = u + 0x7fffu + ((u >> 16) & 1u);   // round-to-nearest-even
    return (u16)(r >> 16);
}

// ---------------------------------------------------------------- converts (one dispatch)
// [0,8192): x->bf16 ; [8192,11264): 3 weight mats ; [11264,11272): bias concat ;
// [11272,11280): zero rowsum[8192]
__global__ void cvt_all(const float* __restrict__ x, u16* __restrict__ xb,
                        const float* __restrict__ w0, const float* __restrict__ w1,
                        const float* __restrict__ w2,
                        u16* __restrict__ o0, u16* __restrict__ o1, u16* __restrict__ o2,
                        const float* __restrict__ qb, const float* __restrict__ kb,
                        float* __restrict__ bqk, float* __restrict__ rowsum)
{
    int b = blockIdx.x;
    if (b >= 11272) {              // zero rowsum: 8 blocks x 256 x 4 floats
        long i = ((long)(b - 11272) * 256 + threadIdx.x) * 4;
        *reinterpret_cast<float4*>(rowsum + i) = make_float4(0.f, 0.f, 0.f, 0.f);
        return;
    }
    if (b >= 11264) {              // bias concat: 8 blocks x 256 = 2048
        int i = (b - 11264) * 256 + threadIdx.x;
        bqk[i] = (i < 1024) ? qb[i] : kb[i - 1024];
        return;
    }
    const float* src; u16* dst; long base;
    if (b < 8192) { src = x; dst = xb; base = (long)b; }
    else {
        int r = b - 8192, seg = r >> 10;
        if (seg == 0)      { src = w0; dst = o0; }
        else if (seg == 1) { src = w1; dst = o1; }
        else               { src = w2; dst = o2; }
        base = (long)(r & 1023);
    }
    long i = (base * 256 + threadIdx.x) * 4;
    float4 v = *reinterpret_cast<const float4*>(src + i);
    uint2 o;
    o.x = (u32)f2bf(v.x) | ((u32)f2bf(v.y) << 16);
    o.y = (u32)f2bf(v.z) | ((u32)f2bf(v.w) << 16);
    *reinterpret_cast<uint2*>(dst + i) = o;
}

// ---------------------------------------------------------------- helpers
__device__ __forceinline__ void async_cp16(const u16* g, u16* l) {
    __builtin_amdgcn_global_load_lds(
        (const __attribute__((address_space(1))) void*)g,
        (__attribute__((address_space(3))) void*)l, 16, 0, 0);
}

#define MEMFENCE asm volatile("" ::: "memory")
__device__ __forceinline__ void barrier_raw() {
    MEMFENCE; __builtin_amdgcn_s_barrier(); MEMFENCE;
}
__device__ __forceinline__ void vmwait(int n) {   // folds when n is a literal
    if      (n == 6) asm volatile("s_waitcnt vmcnt(6)" ::: "memory");
    else if (n == 4) asm volatile("s_waitcnt vmcnt(4)" ::: "memory");
    else if (n == 2) asm volatile("s_waitcnt vmcnt(2)" ::: "memory");
    else             asm volatile("s_waitcnt vmcnt(0)" ::: "memory");
}

// ---------------------------------------------------------------- 8-phase 256x256 core (NT)
// Geometry: BM=BN=256, K-substep 32, 512 threads = 8 waves (2M x 4N), per-wave 128x64 out,
// acc[8][4] 16x16 frags.  LDS = ring of 8 half-tile slots x 16 KiB = 128 KiB.
// Half-tile stream: h even = A(u=h/2) [256 rows x 32 k], h odd = B(u).  Slot = h & 7.
// Schedule ledger (verified):
//   stage: half-tile h issued at global phase h (2 global_load_lds / wave).
//   compute: substep u at phases 2u+5 (X: M-half0, reads A(u)+B(u), 8 ds_read, 16 MFMA)
//            and 2u+6 (Y: M-half1, reads A(u), reuse bf regs, 4 ds_read, 16 MFMA).
//   waits: vmcnt(6) every phase => confirmed stages <= p-3; reads at p need <= p-4  [ok, exact].
//   slot reuse: h+8 staged at phase h+8; last read of h at phase h+6 (A) / h+5 (B); with
//     2 barriers/phase all old reads complete before any wave issues the new stage  [ok].
//   prologue: stage h0..h4, vmcnt(6) confirms h0,h1; tail drains 6 -> 4 -> 2 -> 0.
// LDS swizzle: proven XOR k-group scheme (phys kgroup = logical ^ (row&3)), applied on the
// pre-swizzled GLOBAL source (gload_lds dest must stay linear) and on the ds_read address.
template <bool BF16_OUT, bool EXPOUT>
__device__ __forceinline__ void gemm8_core(
    const u16* __restrict__ A, const u16* __restrict__ B, void* __restrict__ Cv,
    int K, int lda, int ldb, int ldc,
    long tile_m, long tile_n, long cbase,
    const float* __restrict__ bias_col, const float* __restrict__ bias_row,
    float scale, bool rope, float* __restrict__ rowsum, u16* smem)
{
    const int tid  = threadIdx.x;
    const int lane = tid & 63;
    const int wave = tid >> 6;
    const int wm2  = (wave >> 2) * 128;     // wave M offset (0/128)
    const int wn2  = (wave & 3) * 64;       // wave N offset (0/64/128/192)
    const int fm   = lane & 15;
    const int fks  = ((lane >> 4) ^ (lane & 3)) * 8;    // swizzled k-group read offset

    // staging: 512 thr x 16B = 8KB per issue; half-tile (128 rows x 32k x 2B)*2 row-halves
    const int srow = tid >> 2;                           // 0..127
    const int kgl  = ((tid & 3) ^ (srow & 3)) * 8;       // pre-swizzled source k-group
    const u16* Asrc = A + (tile_m + srow) * (long)lda + kgl;
    const u16* Bsrc = B + (tile_n + srow) * (long)ldb + kgl;
    u16* dst0 = smem + tid * 8;                          // linear LDS dest (gload_lds rule)

    const int U = K >> 5;                                // #k-substeps (>= 8 here)

    floatx4 acc[8][4] = {};
    short8 bf[4];

    auto stageA = [&](int v) {
        u16* d = dst0 + ((2 * v) & 7) * 8192;
        const u16* s = Asrc + v * 32;
        async_cp16(s, d);
        async_cp16(s + 128 * (long)lda, d + 4096);
    };
    auto stageB = [&](int v) {
        u16* d = dst0 + ((2 * v + 1) & 7) * 8192;
        const u16* s = Bsrc + v * 32;
        async_cp16(s, d);
        async_cp16(s + 128 * (long)ldb, d + 4096);
    };

    auto phase_pair = [&](int u, int vmx, int vmy, bool stb, bool sta)
        __attribute__((always_inline))
    {
        const u16* Ap = smem + ((2 * u) & 7) * 8192;
        const u16* Bp = smem + ((2 * u + 1) & 7) * 8192;
        short8 af[4];
        // ---- phase X: M-half 0, full N, substep u
        #pragma unroll
        for (int i = 0; i < 4; ++i)
            af[i] = *reinterpret_cast<const short8*>(&Ap[(wm2 + i * 16 + fm) * 32 + fks]);
        #pragma unroll
        for (int j = 0; j < 4; ++j)
            bf[j] = *reinterpret_cast<const short8*>(&Bp[(wn2 + j * 16 + fm) * 32 + fks]);
        if (stb) stageB(u + 2);
        vmwait(vmx);
        barrier_raw();
        __builtin_amdgcn_sched_barrier(0);
        __builtin_amdgcn_s_setprio(1);
        #pragma unroll
        for (int i = 0; i < 4; ++i)
            #pragma unroll
            for (int j = 0; j < 4; ++j)
                acc[i][j] = __builtin_amdgcn_mfma_f32_16x16x32_bf16(af[i], bf[j], acc[i][j], 0, 0, 0);
        __builtin_amdgcn_s_setprio(0);
        __builtin_amdgcn_sched_barrier(0);
        barrier_raw();
        // ---- phase Y: M-half 1, reuse bf
        #pragma unroll
        for (int i = 0; i < 4; ++i)
            af[i] = *reinterpret_cast<const short8*>(&Ap[(wm2 + 64 + i * 16 + fm) * 32 + fks]);
        if (sta) stageA(u + 3);
        vmwait(vmy);
        barrier_raw();
        __builtin_amdgcn_sched_barrier(0);
        __builtin_amdgcn_s_setprio(1);
        #pragma unroll
        for (int i = 0; i < 4; ++i)
            #pragma unroll
            for (int j = 0; j < 4; ++j)
                acc[4 + i][j] = __builtin_amdgcn_mfma_f32_16x16x32_bf16(af[i], bf[j], acc[4 + i][j], 0, 0, 0);
        __builtin_amdgcn_s_setprio(0);
        __builtin_amdgcn_sched_barrier(0);
        barrier_raw();
    };

    // prologue: h0..h4 = A0,B0,A1,B1,A2 ; vmcnt(6) confirms A0,B0
    stageA(0); stageB(0); stageA(1); stageB(1); stageA(2);
    vmwait(6);
    barrier_raw();

    for (int u = 0; u + 3 < U; ++u)
        phase_pair(u, 6, 6, true, true);
    phase_pair(U - 3, 6, 4, true,  false);   // X stages B(U-1), last stage
    phase_pair(U - 2, 2, 0, false, false);
    phase_pair(U - 1, 0, 0, false, false);

    // ---------------- epilogue (per-wave LDS transpose -> vectorized stores; proven code)
    const int q4  = lane >> 4;
    const int c16 = lane & 15;
    float* smemf  = (float*)smem;
    float* myeps  = smemf + wave * (16 * 68);
    const long n0 = tile_n + wn2 + c16 * 4;

    float4 bc4 = make_float4(0.f, 0.f, 0.f, 0.f);
    if (bias_col) bc4 = *reinterpret_cast<const float4*>(bias_col + n0);

    float inv0 = 0.f, inv1 = 0.f;
    if (rope) {
        int p0 = (int)(n0 >> 1);
        inv0 = __expf((float)(p0 & 511)       * -1.79889463e-2f);
        inv1 = __expf((float)((p0 + 1) & 511) * -1.79889463e-2f);
    }

    #pragma unroll
    for (int i = 0; i < 8; ++i) {
        #pragma unroll
        for (int j = 0; j < 4; ++j)
            #pragma unroll
            for (int r = 0; r < 4; ++r)
                myeps[(q4 * 4 + r) * 68 + j * 16 + c16] = acc[i][j][r];
        __syncthreads();
        #pragma unroll
        for (int p = 0; p < 4; ++p) {
            int lrow = p * 4 + q4;
            long m = tile_m + wm2 + i * 16 + lrow;
            float4 v = *reinterpret_cast<const float4*>(&myeps[lrow * 68 + c16 * 4]);
            v.x = v.x * scale + bc4.x;
            v.y = v.y * scale + bc4.y;
            v.z = v.z * scale + bc4.z;
            v.w = v.w * scale + bc4.w;
            if (bias_row) {
                float br = bias_row[m];
                v.x += br; v.y += br; v.z += br; v.w += br;
            }
            if (rope) {
                int s = (int)(m & 2047);
                float a0 = (float)s * inv0, a1 = (float)s * inv1;
                float sn0 = __sinf(a0), cs0 = __cosf(a0);
                float sn1 = __sinf(a1), cs1 = __cosf(a1);
                float x0 = v.x, x1 = v.y, x2 = v.z, x3 = v.w;
                v.x = x0 * cs0 - x1 * sn0;
                v.y = x0 * sn0 + x1 * cs0;
                v.z = x2 * cs1 - x3 * sn1;
                v.w = x2 * sn1 + x3 * cs1;
            }
            if constexpr (EXPOUT) {
                v.x = __expf(v.x); v.y = __expf(v.y);
                v.z = __expf(v.z); v.w = __expf(v.w);
                float s4 = v.x + v.y + v.z + v.w;
                s4 += __shfl_xor(s4, 1);
                s4 += __shfl_xor(s4, 2);
                s4 += __shfl_xor(s4, 4);
                s4 += __shfl_xor(s4, 8);
                if (c16 == 0) atomicAdd(&rowsum[m], s4);
            }
            long off = cbase + m * (long)ldc + n0;
            if constexpr (BF16_OUT) {
                uint2 o;
                o.x = (u32)f2bf(v.x) | ((u32)f2bf(v.y) << 16);
                o.y = (u32)f2bf(v.z) | ((u32)f2bf(v.w) << 16);
                *reinterpret_cast<uint2*>((u16*)Cv + off) = o;
            } else {
                *reinterpret_cast<float4*>((float*)Cv + off) = v;
            }
        }
        __syncthreads();
    }
}

// fused G1 (QK-proj + RoPE, 256 blocks) + G2 (V^T proj, 128 blocks): 384 blocks x 512 thr
__global__ __launch_bounds__(512, 2)
void gemm8_fused12(const u16* __restrict__ xb, const u16* __restrict__ wqk,
                   const u16* __restrict__ wv, u16* __restrict__ QK, u16* __restrict__ VT,
                   const float* __restrict__ bqk, const float* __restrict__ wvb)
{
    u32 id = blockIdx.x;
    id = (id & 7u) * 48u + (id >> 3);          // XCD-contiguous remap (384 % 8 == 0)
    __shared__ alignas(16) u16 smem[65536];    // 128 KiB ring
    if (id < 256u) {                           // G1: M=8192, N=2048, K=1024
        u32 bx = id & 7u, by = id >> 3;
        gemm8_core<true, false>(xb, wqk, QK, 1024, 1024, 1024, 2048,
                                (long)by * 256, (long)bx * 256, 0L,
                                bqk, nullptr, 1.0f, true, nullptr, smem);
    } else {                                   // G2: per-batch M=1024, N=2048, K=1024
        u32 r = id - 256u;
        u32 bz = r >> 5, q = r & 31u, bx = q & 7u, by = q >> 3;
        gemm8_core<true, false>(wv, xb + (long)bz * 2048 * 1024, VT,
                                1024, 1024, 1024, 2048,
                                (long)by * 256, (long)bx * 256, (long)bz * 1024 * 2048,
                                nullptr, wvb, 1.0f, false, nullptr, smem);
    }
}

// G3: P_unnorm[b] = exp(Q[b] @ K[b]^T / 32) -> bf16, rowsum accumulated.  256 blocks (1/CU)
__global__ __launch_bounds__(512, 2)
void gemm8_qkt(const u16* __restrict__ QK, u16* __restrict__ Pbuf,
               float* __restrict__ rsum)
{
    u32 id = blockIdx.x;
    id = (id & 7u) * 32u + (id >> 3);          // XCD-contiguous remap (256 % 8 == 0)
    u32 bz = id >> 6, q = id & 63u, bx = q & 7u, by = q >> 3;
    __shared__ alignas(16) u16 smem[65536];
    const u16* base = QK + (long)bz * 2048 * 2048;
    gemm8_core<true, true>(base, base + 1024, Pbuf, 1024, 2048, 2048, 2048,
                           (long)by * 256, (long)bx * 256, (long)bz * 2048 * 2048,
                           nullptr, nullptr, 0.03125f, false,
                           rsum + (long)bz * 2048, smem);
}

// ---------------------------------------------------------------- G5 core (unchanged, proven)
// 128x64 tile, BK=64 (two 32-panels), 256 threads, 4 waves (each 64x32). 24KB LDS.
template <bool BF16_OUT>
__device__ __forceinline__ void gemm_core_n64(
    const u16* __restrict__ A, const u16* __restrict__ B, void* __restrict__ Cv,
    int K, int lda, int ldb, int ldc,
    long tile_m, long tile_n, long cbase,
    float scale, const float* __restrict__ rowscale, u16* smem)
{
    u16* As = smem;                 // panels: +c*4096 (128x32 each)
    u16* Bs = smem + 8192;          // panels: +c*2048 (64x32 each)

    const int tid  = threadIdx.x;
    const int lane = tid & 63;
    const int wave = tid >> 6;
    const int wm = (wave >> 1) << 6;       // 0 / 64
    const int wn = (wave & 1) << 5;        // 0 / 32

    floatx4 acc[4][2] = {};

    const int srow = tid >> 2;
    const int skp  = (((tid & 3) ^ (srow & 3))) * 8;
    const u16* Ag = A + (tile_m + srow) * (long)lda + skp;
    const u16* Bg = B + (tile_n + srow) * (long)ldb + skp;
    u16* Asl = &As[tid * 8];
    u16* Bsl = &Bs[tid * 8];

    const int fm  = lane & 15;
    const int fks = (((lane >> 4) ^ (lane & 3))) * 8;

    for (int k0 = 0; k0 < K; k0 += 64) {
        async_cp16(Ag,                       Asl);
        async_cp16(Ag + 64 * (long)lda,      Asl + 64 * 32);
        async_cp16(Ag + 32,                  Asl + 4096);
        async_cp16(Ag + 32 + 64 * (long)lda, Asl + 4096 + 64 * 32);
        async_cp16(Bg,                       Bsl);
        async_cp16(Bg + 32,                  Bsl + 2048);
        Ag += 64; Bg += 64;
        __syncthreads();

        #pragma unroll
        for (int c = 0; c < 2; ++c) {
            const u16* Ap = As + c * 4096;
            const u16* Bp = Bs + c * 2048;
            short8 af[4], bfr[2];
            #pragma unroll
            for (int i = 0; i < 4; ++i)
                af[i] = *reinterpret_cast<const short8*>(&Ap[(wm + i * 16 + fm) * 32 + fks]);
            #pragma unroll
            for (int j = 0; j < 2; ++j)
                bfr[j] = *reinterpret_cast<const short8*>(&Bp[(wn + j * 16 + fm) * 32 + fks]);
            #pragma unroll
            for (int i = 0; i < 4; ++i)
                #pragma unroll
                for (int j = 0; j < 2; ++j)
                    acc[i][j] = __builtin_amdgcn_mfma_f32_16x16x32_bf16(af[i], bfr[j], acc[i][j], 0, 0, 0);
        }
        __syncthreads();
    }

    const int q4  = lane >> 4;
    const int c16 = lane & 15;
    float* smemf = (float*)smem;
    float* myeps = smemf + wave * (16 * 36);
    const long n0 = tile_n + wn + c16 * 2;

    #pragma unroll
    for (int i = 0; i < 4; ++i) {
        #pragma unroll
        for (int j = 0; j < 2; ++j)
            #pragma unroll
            for (int r = 0; r < 4; ++r)
                myeps[(q4 * 4 + r) * 36 + j * 16 + c16] = acc[i][j][r];
        __syncthreads();
        #pragma unroll
        for (int p = 0; p < 4; ++p) {
            int lrow = p * 4 + q4;
            long m = tile_m + wm + i * 16 + lrow;
            float2 v = *reinterpret_cast<const float2*>(&myeps[lrow * 36 + c16 * 2]);
            float sc = scale;
            if (rowscale) sc *= 1.0f / rowscale[m];
            v.x *= sc; v.y *= sc;
            long off = cbase + m * (long)ldc + n0;
            if constexpr (BF16_OUT) {
                *reinterpret_cast<u32*>((u16*)Cv + off) =
                    (u32)f2bf(v.x) | ((u32)f2bf(v.y) << 16);
            } else {
                *reinterpret_cast<float2*>((float*)Cv + off) = v;
            }
        }
        __syncthreads();
    }
}

template <bool BF16_OUT>
__global__ __launch_bounds__(256)
void gemm_nt_n64(const u16* __restrict__ A, const u16* __restrict__ B, void* __restrict__ Cv,
                 int K, int lda, int ldb, int ldc,
                 long sA, long sB, long sC, float scale,
                 const float* __restrict__ rowscale)
{
    const u32 gx = gridDim.x, gy = gridDim.y;
    u32 id = blockIdx.x + gx * (blockIdx.y + gy * blockIdx.z);
    const u32 G = gx * gy * gridDim.z;
    if ((G & 7u) == 0u) id = (id & 7u) * (G >> 3) + (id >> 3);
    const u32 bx = id % gx;
    const u32 t1 = id / gx;
    const u32 by = t1 % gy;
    const u32 bz = t1 / gy;

    __shared__ alignas(16) u16 smem[12288];  // 24576 B
    gemm_core_n64<BF16_OUT>(A + (long)bz * sA, B + (long)bz * sB, Cv,
                            K, lda, ldb, ldc,
                            (long)by * 128, (long)bx * 64, (long)bz * sC,
                            scale, rowscale ? rowscale + (long)bz * 2048 : nullptr, smem);
}

// ---------------------------------------------------------------- launch
extern "C" void kernel_launch(void* const* d_in, const int* in_sizes, int n_in,
                              void* d_out, int out_size, void* d_ws, size_t ws_size,
                              hipStream_t stream)
{
    const float* x   = (const float*)d_in[0];
    const float* wqw = (const float*)d_in[1];
    const float* wqb = (const float*)d_in[2];
    const float* wkw = (const float*)d_in[3];
    const float* wkb = (const float*)d_in[4];
    const float* wvw = (const float*)d_in[5];
    const float* wvb = (const float*)d_in[6];
    float* out = (float*)d_out;

    char* ws = (char*)d_ws;
    const size_t MB = 1ull << 20;
    u16*   Pbuf = (u16*)(ws + 64 * MB);      // 32MB [4][2048][2048] bf16 P_unnorm = exp(S)
    u16*   QK   = (u16*)(ws + 96 * MB);      // 32MB [8192][2048] bf16 (Q | K), RoPE applied
    u16*   VT   = (u16*)(ws + 128 * MB);     // 16MB [4][1024][2048] bf16 (V transposed)
    float* rsum = (float*)(ws + 144 * MB);   // 32KB [8192] f32 softmax row sums
    u16*   xb    = (u16*)(ws + 0);           // 16MB [8192][1024]
    u16*   wqk   = (u16*)(ws + 16 * MB);     //  4MB [2048][1024]
    u16*   wvbuf = (u16*)(ws + 20 * MB);     //  2MB [1024][1024]
    float* bqk   = (float*)(ws + 22 * MB);   //  8KB [2048]

    // 1. all dtype conversions + bias concat + rowsum zeroing
    cvt_all<<<dim3(11280), 256, 0, stream>>>(x, xb, wqw, wkw, wvw,
                                             wqk, wqk + 1024 * 1024, wvbuf,
                                             wqb, wkb, bqk, rsum);

    // 2. fused G1 + G2 on the 8-phase 256^2 core
    gemm8_fused12<<<dim3(384), 512, 0, stream>>>(xb, wqk, wvbuf, QK, VT, bqk, wvb);

    // 3. G3 on the 8-phase core: exp(QK^T/32) -> bf16 + rowsum
    gemm8_qkt<<<dim3(256), 512, 0, stream>>>(QK, Pbuf, rsum);

    // 4. G5: out[b] = (P_unnorm[b] @ VT[b]^T) / rowsum   (proven n64 core, next round's target)
    gemm_nt_n64<false><<<dim3(16, 16, 4), 256, 0, stream>>>(
        Pbuf, VT, out, 2048, 2048, 2048, 1024,
        2048L * 2048, 1024L * 2048, 2048L * 1024, 1.0f, rsum);

    (void)in_sizes; (void)n_in; (void)out_size; (void)ws_size;
}

// Round 2
// 264.335 us; speedup vs baseline: 1.0265x; 1.0265x over previous
//
#include <hip/hip_runtime.h>
#include <cstdint>

using u16 = unsigned short;
using u32 = unsigned int;

typedef __attribute__((ext_vector_type(8))) short short8;   // 8 bf16 (A/B frag)
typedef __attribute__((ext_vector_type(4))) float floatx4;  // C frag

__device__ __forceinline__ u16 f2bf(float f) {
    u32 u = __float_as_uint(f);
    u32 r = u + 0x7fffu + ((u >> 16) & 1u);   // round-to-nearest-even
    return (u16)(r >> 16);
}

// ---------------------------------------------------------------- converts (one dispatch)
// [0,8192): x->bf16 ; [8192,11264): 3 weight mats ; [11264,11272): bias concat ;
// [11272,11280): zero rowsum[8192]
__global__ void cvt_all(const float* __restrict__ x, u16* __restrict__ xb,
                        const float* __restrict__ w0, const float* __restrict__ w1,
                        const float* __restrict__ w2,
                        u16* __restrict__ o0, u16* __restrict__ o1, u16* __restrict__ o2,
                        const float* __restrict__ qb, const float* __restrict__ kb,
                        float* __restrict__ bqk, float* __restrict__ rowsum)
{
    int b = blockIdx.x;
    if (b >= 11272) {              // zero rowsum: 8 blocks x 256 x 4 floats
        long i = ((long)(b - 11272) * 256 + threadIdx.x) * 4;
        *reinterpret_cast<float4*>(rowsum + i) = make_float4(0.f, 0.f, 0.f, 0.f);
        return;
    }
    if (b >= 11264) {              // bias concat: 8 blocks x 256 = 2048
        int i = (b - 11264) * 256 + threadIdx.x;
        bqk[i] = (i < 1024) ? qb[i] : kb[i - 1024];
        return;
    }
    const float* src; u16* dst; long base;
    if (b < 8192) { src = x; dst = xb; base = (long)b; }
    else {
        int r = b - 8192, seg = r >> 10;
        if (seg == 0)      { src = w0; dst = o0; }
        else if (seg == 1) { src = w1; dst = o1; }
        else               { src = w2; dst = o2; }
        base = (long)(r & 1023);
    }
    long i = (base * 256 + threadIdx.x) * 4;
    float4 v = *reinterpret_cast<const float4*>(src + i);
    uint2 o;
    o.x = (u32)f2bf(v.x) | ((u32)f2bf(v.y) << 16);
    o.y = (u32)f2bf(v.z) | ((u32)f2bf(v.w) << 16);
    *reinterpret_cast<uint2*>(dst + i) = o;
}

// ---------------------------------------------------------------- helpers
__device__ __forceinline__ void async_cp16(const u16* g, u16* l) {
    __builtin_amdgcn_global_load_lds(
        (const __attribute__((address_space(1))) void*)g,
        (__attribute__((address_space(3))) void*)l, 16, 0, 0);
}

#define MEMFENCE asm volatile("" ::: "memory")
__device__ __forceinline__ void barrier_raw() {
    MEMFENCE; __builtin_amdgcn_s_barrier(); MEMFENCE;
}
__device__ __forceinline__ void vmwait(int n) {   // folds when n is a literal
    if      (n == 6) asm volatile("s_waitcnt vmcnt(6)" ::: "memory");
    else if (n == 4) asm volatile("s_waitcnt vmcnt(4)" ::: "memory");
    else if (n == 2) asm volatile("s_waitcnt vmcnt(2)" ::: "memory");
    else             asm volatile("s_waitcnt vmcnt(0)" ::: "memory");
}

// ---------------------------------------------------------------- 8-phase 256x256 core (NT)
// Geometry: BM=BN=256, K-substep 32, 512 threads = 8 waves (2M x 4N), per-wave 128x64 out,
// acc[8][4] 16x16 frags.  LDS = ring of 8 half-tile slots x 16 KiB = 128 KiB.
// Half-tile stream: h even = A(u=h/2) [256 rows x 32 k], h odd = B(u).  Slot = h & 7.
// Schedule ledger (verified round 1, correctness PASSED):
//   stage: half-tile h issued at global phase h (2 global_load_lds / wave).
//   compute: substep u at phases 2u+5 (X: M-half0, reads A(u)+B(u), 8 ds_read, 16 MFMA)
//            and 2u+6 (Y: M-half1, reads A(u), reuse bf regs, 4 ds_read, 16 MFMA).
//   waits: vmcnt(6) every phase => confirmed stages <= p-3; reads at p need <= p-4  [ok].
//   slot reuse: h+8 staged at phase h+8; last read of h at h+6; 2 barriers/phase  [ok].
//   prologue: stage h0..h4, vmcnt(6) confirms h0,h1; tail drains 6 -> 4 -> 2 -> 0.
// LDS swizzle (ROUND-2 FIX, T2): phys kgroup = logical ^ f(row), f(row)=(row>>1)&3.
//   Bank walk: frag-read lane l (row=base16+(l&15), G=l>>4) has bank-start
//   (16*(l&15) + 4*(G ^ f))%32; with f=(r>>1)&3 each aligned 8-lane octet covers all
//   32 banks exactly once -> ds_read_b128 conflict-free.  (Old f=r&3 hit half the
//   banks 2-way: SQ_LDS_BANK_CONFLICT 5.1M, MfmaUtil capped at 23%.)
//   Applied on the pre-swizzled GLOBAL source (gload_lds dest stays linear, rule #21)
//   and on the ds_read address.  Row-base multiples of 16 keep f lane-computable.
template <bool BF16_OUT, bool EXPOUT>
__device__ __forceinline__ void gemm8_core(
    const u16* __restrict__ A, const u16* __restrict__ B, void* __restrict__ Cv,
    int K, int lda, int ldb, int ldc,
    long tile_m, long tile_n, long cbase,
    const float* __restrict__ bias_col, const float* __restrict__ bias_row,
    float scale, bool rope, float* __restrict__ rowsum, u16* smem)
{
    const int tid  = threadIdx.x;
    const int lane = tid & 63;
    const int wave = tid >> 6;
    const int wm2  = (wave >> 2) * 128;     // wave M offset (0/128)
    const int wn2  = (wave & 3) * 64;       // wave N offset (0/64/128/192)
    const int fm   = lane & 15;
    const int fks  = (((lane >> 4) ^ ((lane >> 1) & 3))) * 8;  // conflict-free k-group read

    // staging: 512 thr x 16B = 8KB per issue; half-tile = 2 issues (rows 0-127, 128-255)
    const int srow = tid >> 2;                            // 0..127
    const int kgl  = ((tid & 3) ^ ((tid >> 3) & 3)) * 8;  // pre-swizzled source k-group
    const u16* Asrc = A + (tile_m + srow) * (long)lda + kgl;
    const u16* Bsrc = B + (tile_n + srow) * (long)ldb + kgl;
    u16* dst0 = smem + tid * 8;                           // linear LDS dest (gload_lds rule)

    const int U = K >> 5;                                 // #k-substeps (>= 8 here)

    floatx4 acc[8][4] = {};
    short8 bf[4];

    auto stageA = [&](int v) {
        u16* d = dst0 + ((2 * v) & 7) * 8192;
        const u16* s = Asrc + v * 32;
        async_cp16(s, d);
        async_cp16(s + 128 * (long)lda, d + 4096);
    };
    auto stageB = [&](int v) {
        u16* d = dst0 + ((2 * v + 1) & 7) * 8192;
        const u16* s = Bsrc + v * 32;
        async_cp16(s, d);
        async_cp16(s + 128 * (long)ldb, d + 4096);
    };

    auto phase_pair = [&](int u, int vmx, int vmy, bool stb, bool sta)
        __attribute__((always_inline))
    {
        const u16* Ap = smem + ((2 * u) & 7) * 8192;
        const u16* Bp = smem + ((2 * u + 1) & 7) * 8192;
        short8 af[4];
        // ---- phase X: M-half 0, full N, substep u
        #pragma unroll
        for (int i = 0; i < 4; ++i)
            af[i] = *reinterpret_cast<const short8*>(&Ap[(wm2 + i * 16 + fm) * 32 + fks]);
        #pragma unroll
        for (int j = 0; j < 4; ++j)
            bf[j] = *reinterpret_cast<const short8*>(&Bp[(wn2 + j * 16 + fm) * 32 + fks]);
        if (stb) stageB(u + 2);
        vmwait(vmx);
        barrier_raw();
        __builtin_amdgcn_sched_barrier(0);
        __builtin_amdgcn_s_setprio(1);
        #pragma unroll
        for (int i = 0; i < 4; ++i)
            #pragma unroll
            for (int j = 0; j < 4; ++j)
                acc[i][j] = __builtin_amdgcn_mfma_f32_16x16x32_bf16(af[i], bf[j], acc[i][j], 0, 0, 0);
        __builtin_amdgcn_s_setprio(0);
        __builtin_amdgcn_sched_barrier(0);
        barrier_raw();
        // ---- phase Y: M-half 1, reuse bf
        #pragma unroll
        for (int i = 0; i < 4; ++i)
            af[i] = *reinterpret_cast<const short8*>(&Ap[(wm2 + 64 + i * 16 + fm) * 32 + fks]);
        if (sta) stageA(u + 3);
        vmwait(vmy);
        barrier_raw();
        __builtin_amdgcn_sched_barrier(0);
        __builtin_amdgcn_s_setprio(1);
        #pragma unroll
        for (int i = 0; i < 4; ++i)
            #pragma unroll
            for (int j = 0; j < 4; ++j)
                acc[4 + i][j] = __builtin_amdgcn_mfma_f32_16x16x32_bf16(af[i], bf[j], acc[4 + i][j], 0, 0, 0);
        __builtin_amdgcn_s_setprio(0);
        __builtin_amdgcn_sched_barrier(0);
        barrier_raw();
    };

    // prologue: h0..h4 = A0,B0,A1,B1,A2 ; vmcnt(6) confirms A0,B0
    stageA(0); stageB(0); stageA(1); stageB(1); stageA(2);
    vmwait(6);
    barrier_raw();

    for (int u = 0; u + 3 < U; ++u)
        phase_pair(u, 6, 6, true, true);
    phase_pair(U - 3, 6, 4, true,  false);   // X stages B(U-1), last stage
    phase_pair(U - 2, 2, 0, false, false);
    phase_pair(U - 1, 0, 0, false, false);

    // ---------------- epilogue (per-wave LDS transpose -> vectorized stores; proven code)
    // Bank audit: write stride 68 f32 -> q4 offsets {0,16,0,16} = 2-way (free);
    // read float4: 16 lanes cover 32 banks 2x (free).  Untouched.
    const int q4  = lane >> 4;
    const int c16 = lane & 15;
    float* smemf  = (float*)smem;
    float* myeps  = smemf + wave * (16 * 68);
    const long n0 = tile_n + wn2 + c16 * 4;

    float4 bc4 = make_float4(0.f, 0.f, 0.f, 0.f);
    if (bias_col) bc4 = *reinterpret_cast<const float4*>(bias_col + n0);

    float inv0 = 0.f, inv1 = 0.f;
    if (rope) {
        int p0 = (int)(n0 >> 1);
        inv0 = __expf((float)(p0 & 511)       * -1.79889463e-2f);
        inv1 = __expf((float)((p0 + 1) & 511) * -1.79889463e-2f);
    }

    #pragma unroll
    for (int i = 0; i < 8; ++i) {
        #pragma unroll
        for (int j = 0; j < 4; ++j)
            #pragma unroll
            for (int r = 0; r < 4; ++r)
                myeps[(q4 * 4 + r) * 68 + j * 16 + c16] = acc[i][j][r];
        __syncthreads();
        #pragma unroll
        for (int p = 0; p < 4; ++p) {
            int lrow = p * 4 + q4;
            long m = tile_m + wm2 + i * 16 + lrow;
            float4 v = *reinterpret_cast<const float4*>(&myeps[lrow * 68 + c16 * 4]);
            v.x = v.x * scale + bc4.x;
            v.y = v.y * scale + bc4.y;
            v.z = v.z * scale + bc4.z;
            v.w = v.w * scale + bc4.w;
            if (bias_row) {
                float br = bias_row[m];
                v.x += br; v.y += br; v.z += br; v.w += br;
            }
            if (rope) {
                int s = (int)(m & 2047);
                float a0 = (float)s * inv0, a1 = (float)s * inv1;
                float sn0 = __sinf(a0), cs0 = __cosf(a0);
                float sn1 = __sinf(a1), cs1 = __cosf(a1);
                float x0 = v.x, x1 = v.y, x2 = v.z, x3 = v.w;
                v.x = x0 * cs0 - x1 * sn0;
                v.y = x0 * sn0 + x1 * cs0;
                v.z = x2 * cs1 - x3 * sn1;
                v.w = x2 * sn1 + x3 * cs1;
            }
            if constexpr (EXPOUT) {
                v.x = __expf(v.x); v.y = __expf(v.y);
                v.z = __expf(v.z); v.w = __expf(v.w);
                float s4 = v.x + v.y + v.z + v.w;
                s4 += __shfl_xor(s4, 1);
                s4 += __shfl_xor(s4, 2);
                s4 += __shfl_xor(s4, 4);
                s4 += __shfl_xor(s4, 8);
                if (c16 == 0) atomicAdd(&rowsum[m], s4);
            }
            long off = cbase + m * (long)ldc + n0;
            if constexpr (BF16_OUT) {
                uint2 o;
                o.x = (u32)f2bf(v.x) | ((u32)f2bf(v.y) << 16);
                o.y = (u32)f2bf(v.z) | ((u32)f2bf(v.w) << 16);
                *reinterpret_cast<uint2*>((u16*)Cv + off) = o;
            } else {
                *reinterpret_cast<float4*>((float*)Cv + off) = v;
            }
        }
        __syncthreads();
    }
}

// fused G1 (QK-proj + RoPE, 256 blocks) + G2 (V^T proj, 128 blocks): 384 blocks x 512 thr
// NOTE: 1 block/CU => 384 jobs = 256-round + 128-round tail (~25% idle); all
// rearrangements cost the same (split dispatch / half-fill G2 / BN=128 all ~equal) —
// verified arithmetic round 1; not worth restructuring.
__global__ __launch_bounds__(512, 2)
void gemm8_fused12(const u16* __restrict__ xb, const u16* __restrict__ wqk,
                   const u16* __restrict__ wv, u16* __restrict__ QK, u16* __restrict__ VT,
                   const float* __restrict__ bqk, const float* __restrict__ wvb)
{
    u32 id = blockIdx.x;
    id = (id & 7u) * 48u + (id >> 3);          // XCD-contiguous remap (384 % 8 == 0)
    __shared__ alignas(16) u16 smem[65536];    // 128 KiB ring
    if (id < 256u) {                           // G1: M=8192, N=2048, K=1024
        u32 bx = id & 7u, by = id >> 3;
        gemm8_core<true, false>(xb, wqk, QK, 1024, 1024, 1024, 2048,
                                (long)by * 256, (long)bx * 256, 0L,
                                bqk, nullptr, 1.0f, true, nullptr, smem);
    } else {                                   // G2: per-batch M=1024, N=2048, K=1024
        u32 r = id - 256u;
        u32 bz = r >> 5, q = r & 31u, bx = q & 7u, by = q >> 3;
        gemm8_core<true, false>(wv, xb + (long)bz * 2048 * 1024, VT,
                                1024, 1024, 1024, 2048,
                                (long)by * 256, (long)bx * 256, (long)bz * 1024 * 2048,
                                nullptr, wvb, 1.0f, false, nullptr, smem);
    }
}

// G3: P_unnorm[b] = exp(Q[b] @ K[b]^T / 32) -> bf16, rowsum accumulated.  256 blocks (1/CU)
__global__ __launch_bounds__(512, 2)
void gemm8_qkt(const u16* __restrict__ QK, u16* __restrict__ Pbuf,
               float* __restrict__ rsum)
{
    u32 id = blockIdx.x;
    id = (id & 7u) * 32u + (id >> 3);          // XCD-contiguous remap (256 % 8 == 0)
    u32 bz = id >> 6, q = id & 63u, bx = q & 7u, by = q >> 3;
    __shared__ alignas(16) u16 smem[65536];
    const u16* base = QK + (long)bz * 2048 * 2048;
    gemm8_core<true, true>(base, base + 1024, Pbuf, 1024, 2048, 2048, 2048,
                           (long)by * 256, (long)bx * 256, (long)bz * 2048 * 2048,
                           nullptr, nullptr, 0.03125f, false,
                           rsum + (long)bz * 2048, smem);
}

// ---------------------------------------------------------------- G5 core (unchanged, proven)
// 128x64 tile, BK=64 (two 32-panels), 256 threads, 4 waves (each 64x32). 24KB LDS.
// 2-phase structure: T2 swizzle-fix is null here (regime gate, m252) — left as-is.
template <bool BF16_OUT>
__device__ __forceinline__ void gemm_core_n64(
    const u16* __restrict__ A, const u16* __restrict__ B, void* __restrict__ Cv,
    int K, int lda, int ldb, int ldc,
    long tile_m, long tile_n, long cbase,
    float scale, const float* __restrict__ rowscale, u16* smem)
{
    u16* As = smem;                 // panels: +c*4096 (128x32 each)
    u16* Bs = smem + 8192;          // panels: +c*2048 (64x32 each)

    const int tid  = threadIdx.x;
    const int lane = tid & 63;
    const int wave = tid >> 6;
    const int wm = (wave >> 1) << 6;       // 0 / 64
    const int wn = (wave & 1) << 5;        // 0 / 32

    floatx4 acc[4][2] = {};

    const int srow = tid >> 2;
    const int skp  = (((tid & 3) ^ (srow & 3))) * 8;
    const u16* Ag = A + (tile_m + srow) * (long)lda + skp;
    const u16* Bg = B + (tile_n + srow) * (long)ldb + skp;
    u16* Asl = &As[tid * 8];
    u16* Bsl = &Bs[tid * 8];

    const int fm  = lane & 15;
    const int fks = (((lane >> 4) ^ (lane & 3))) * 8;

    for (int k0 = 0; k0 < K; k0 += 64) {
        async_cp16(Ag,                       Asl);
        async_cp16(Ag + 64 * (long)lda,      Asl + 64 * 32);
        async_cp16(Ag + 32,                  Asl + 4096);
        async_cp16(Ag + 32 + 64 * (long)lda, Asl + 4096 + 64 * 32);
        async_cp16(Bg,                       Bsl);
        async_cp16(Bg + 32,                  Bsl + 2048);
        Ag += 64; Bg += 64;
        __syncthreads();

        #pragma unroll
        for (int c = 0; c < 2; ++c) {
            const u16* Ap = As + c * 4096;
            const u16* Bp = Bs + c * 2048;
            short8 af[4], bfr[2];
            #pragma unroll
            for (int i = 0; i < 4; ++i)
                af[i] = *reinterpret_cast<const short8*>(&Ap[(wm + i * 16 + fm) * 32 + fks]);
            #pragma unroll
            for (int j = 0; j < 2; ++j)
                bfr[j] = *reinterpret_cast<const short8*>(&Bp[(wn + j * 16 + fm) * 32 + fks]);
            #pragma unroll
            for (int i = 0; i < 4; ++i)
                #pragma unroll
                for (int j = 0; j < 2; ++j)
                    acc[i][j] = __builtin_amdgcn_mfma_f32_16x16x32_bf16(af[i], bfr[j], acc[i][j], 0, 0, 0);
        }
        __syncthreads();
    }

    const int q4  = lane >> 4;
    const int c16 = lane & 15;
    float* smemf = (float*)smem;
    float* myeps = smemf + wave * (16 * 36);
    const long n0 = tile_n + wn + c16 * 2;

    #pragma unroll
    for (int i = 0; i < 4; ++i) {
        #pragma unroll
        for (int j = 0; j < 2; ++j)
            #pragma unroll
            for (int r = 0; r < 4; ++r)
                myeps[(q4 * 4 + r) * 36 + j * 16 + c16] = acc[i][j][r];
        __syncthreads();
        #pragma unroll
        for (int p = 0; p < 4; ++p) {
            int lrow = p * 4 + q4;
            long m = tile_m + wm + i * 16 + lrow;
            float2 v = *reinterpret_cast<const float2*>(&myeps[lrow * 36 + c16 * 2]);
            float sc = scale;
            if (rowscale) sc *= 1.0f / rowscale[m];
            v.x *= sc; v.y *= sc;
            long off = cbase + m * (long)ldc + n0;
            if constexpr (BF16_OUT) {
                *reinterpret_cast<u32*>((u16*)Cv + off) =
                    (u32)f2bf(v.x) | ((u32)f2bf(v.y) << 16);
            } else {
                *reinterpret_cast<float2*>((float*)Cv + off) = v;
            }
        }
        __syncthreads();
    }
}

template <bool BF16_OUT>
__global__ __launch_bounds__(256)
void gemm_nt_n64(const u16* __restrict__ A, const u16* __restrict__ B, void* __restrict__ Cv,
                 int K, int lda, int ldb, int ldc,
                 long sA, long sB, long sC, float scale,
                 const float* __restrict__ rowscale)
{
    const u32 gx = gridDim.x, gy = gridDim.y;
    u32 id = blockIdx.x + gx * (blockIdx.y + gy * blockIdx.z);
    const u32 G = gx * gy * gridDim.z;
    if ((G & 7u) == 0u) id = (id & 7u) * (G >> 3) + (id >> 3);
    const u32 bx = id % gx;
    const u32 t1 = id / gx;
    const u32 by = t1 % gy;
    const u32 bz = t1 / gy;

    __shared__ alignas(16) u16 smem[12288];  // 24576 B
    gemm_core_n64<BF16_OUT>(A + (long)bz * sA, B + (long)bz * sB, Cv,
                            K, lda, ldb, ldc,
                            (long)by * 128, (long)bx * 64, (long)bz * sC,
                            scale, rowscale ? rowscale + (long)bz * 2048 : nullptr, smem);
}

// ---------------------------------------------------------------- launch
extern "C" void kernel_launch(void* const* d_in, const int* in_sizes, int n_in,
                              void* d_out, int out_size, void* d_ws, size_t ws_size,
                              hipStream_t stream)
{
    const float* x   = (const float*)d_in[0];
    const float* wqw = (const float*)d_in[1];
    const float* wqb = (const float*)d_in[2];
    const float* wkw = (const float*)d_in[3];
    const float* wkb = (const float*)d_in[4];
    const float* wvw = (const float*)d_in[5];
    const float* wvb = (const float*)d_in[6];
    float* out = (float*)d_out;

    char* ws = (char*)d_ws;
    const size_t MB = 1ull << 20;
    u16*   Pbuf = (u16*)(ws + 64 * MB);      // 32MB [4][2048][2048] bf16 P_unnorm = exp(S)
    u16*   QK   = (u16*)(ws + 96 * MB);      // 32MB [8192][2048] bf16 (Q | K), RoPE applied
    u16*   VT   = (u16*)(ws + 128 * MB);     // 16MB [4][1024][2048] bf16 (V transposed)
    float* rsum = (float*)(ws + 144 * MB);   // 32KB [8192] f32 softmax row sums
    u16*   xb    = (u16*)(ws + 0);           // 16MB [8192][1024]
    u16*   wqk   = (u16*)(ws + 16 * MB);     //  4MB [2048][1024]
    u16*   wvbuf = (u16*)(ws + 20 * MB);     //  2MB [1024][1024]
    float* bqk   = (float*)(ws + 22 * MB);   //  8KB [2048]

    // 1. all dtype conversions + bias concat + rowsum zeroing
    cvt_all<<<dim3(11280), 256, 0, stream>>>(x, xb, wqw, wkw, wvw,
                                             wqk, wqk + 1024 * 1024, wvbuf,
                                             wqb, wkb, bqk, rsum);

    // 2. fused G1 + G2 on the 8-phase 256^2 core (conflict-free swizzle)
    gemm8_fused12<<<dim3(384), 512, 0, stream>>>(xb, wqk, wvbuf, QK, VT, bqk, wvb);

    // 3. G3 on the 8-phase core: exp(QK^T/32) -> bf16 + rowsum
    gemm8_qkt<<<dim3(256), 512, 0, stream>>>(QK, Pbuf, rsum);

    // 4. G5: out[b] = (P_unnorm[b] @ VT[b]^T) / rowsum   (proven n64 core)
    gemm_nt_n64<false><<<dim3(16, 16, 4), 256, 0, stream>>>(
        Pbuf, VT, out, 2048, 2048, 2048, 1024,
        2048L * 2048, 1024L * 2048, 2048L * 1024, 1.0f, rsum);

    (void)in_sizes; (void)n_in; (void)out_size; (void)ws_size;
}

// Round 3
// 262.710 us; speedup vs baseline: 1.0329x; 1.0062x over previous
//
#include <hip/hip_runtime.h>
#include <cstdint>

using u16 = unsigned short;
using u32 = unsigned int;

typedef __attribute__((ext_vector_type(8))) short short8;   // 8 bf16 (A/B frag)
typedef __attribute__((ext_vector_type(4))) float floatx4;  // C frag

__device__ __forceinline__ u16 f2bf(float f) {
    u32 u = __float_as_uint(f);
    u32 r = u + 0x7fffu + ((u >> 16) & 1u);   // round-to-nearest-even
    return (u16)(r >> 16);
}

// ---------------------------------------------------------------- converts (one dispatch)
// [0,8192): x->bf16 ; [8192,11264): 3 weight mats ; [11264,11272): bias concat ;
// [11272,11280): zero rowsum[8192]
__global__ void cvt_all(const float* __restrict__ x, u16* __restrict__ xb,
                        const float* __restrict__ w0, const float* __restrict__ w1,
                        const float* __restrict__ w2,
                        u16* __restrict__ o0, u16* __restrict__ o1, u16* __restrict__ o2,
                        const float* __restrict__ qb, const float* __restrict__ kb,
                        float* __restrict__ bqk, float* __restrict__ rowsum)
{
    int b = blockIdx.x;
    if (b >= 11272) {              // zero rowsum: 8 blocks x 256 x 4 floats
        long i = ((long)(b - 11272) * 256 + threadIdx.x) * 4;
        *reinterpret_cast<float4*>(rowsum + i) = make_float4(0.f, 0.f, 0.f, 0.f);
        return;
    }
    if (b >= 11264) {              // bias concat: 8 blocks x 256 = 2048
        int i = (b - 11264) * 256 + threadIdx.x;
        bqk[i] = (i < 1024) ? qb[i] : kb[i - 1024];
        return;
    }
    const float* src; u16* dst; long base;
    if (b < 8192) { src = x; dst = xb; base = (long)b; }
    else {
        int r = b - 8192, seg = r >> 10;
        if (seg == 0)      { src = w0; dst = o0; }
        else if (seg == 1) { src = w1; dst = o1; }
        else               { src = w2; dst = o2; }
        base = (long)(r & 1023);
    }
    long i = (base * 256 + threadIdx.x) * 4;
    float4 v = *reinterpret_cast<const float4*>(src + i);
    uint2 o;
    o.x = (u32)f2bf(v.x) | ((u32)f2bf(v.y) << 16);
    o.y = (u32)f2bf(v.z) | ((u32)f2bf(v.w) << 16);
    *reinterpret_cast<uint2*>(dst + i) = o;
}

// ---------------------------------------------------------------- helpers
__device__ __forceinline__ void async_cp16(const u16* g, u16* l) {
    __builtin_amdgcn_global_load_lds(
        (const __attribute__((address_space(1))) void*)g,
        (__attribute__((address_space(3))) void*)l, 16, 0, 0);
}

#define MEMFENCE asm volatile("" ::: "memory")
__device__ __forceinline__ void barrier_raw() {
    MEMFENCE; __builtin_amdgcn_s_barrier(); MEMFENCE;
}
__device__ __forceinline__ void vmwait(int n) {   // folds when n is a literal; n<0 = skip
    if      (n == 6) asm volatile("s_waitcnt vmcnt(6)" ::: "memory");
    else if (n == 4) asm volatile("s_waitcnt vmcnt(4)" ::: "memory");
    else if (n == 2) asm volatile("s_waitcnt vmcnt(2)" ::: "memory");
    else if (n == 0) asm volatile("s_waitcnt vmcnt(0)" ::: "memory");
}

// ---------------------------------------------------------------- 8-phase 256x256 core (NT)
// Geometry: BM=BN=256, K-substep 32, 512 threads = 8 waves (2M x 4N), per-wave 128x64 out,
// acc[8][4] 16x16 frags.  LDS = ring of 8 half-tile slots x 16 KiB = 128 KiB.
// Half-tile stream: h even = A(u=h/2) [256 rows x 32 k], h odd = B(u).  Slot = h & 7.
// Schedule ledger (ROUND-3: wait cadence halved — T4 fix):
//   stage: half-tile h issued at phase h (X(u) stages B(u+2)@2u+5; Y(u) stages A(u+3)@2u+6).
//   compute: substep u at phases 2u+5 (X: M-half0, reads A(u)+B(u)) and 2u+6 (Y: M-half1,
//            reads A(u), reuses bf regs).
//   waits: ONE vmcnt(6) per substep, in X only (round-2 had one per phase -> 3-phase
//     confirm budget ~ HBM latency -> stall every phase; MfmaUtil pinned at 24%).
//     X(u)'s vmcnt(6): issued through B(u+2); newest 3 half-tiles = B(u+2),A(u+2),B(u+1)
//     -> confirms <= A(u+1) \supseteq {A(u),B(u)}  [ok].  Y has no wait: reads A(u),
//     confirmed at X(u) and barrier-ordered  [ok].  Budget now 4-5 phases (>HBM lat).
//   slot reuse: stage issue at phase h lands >= 2 barriers after last read of occupant
//     h-8 (last read at h-2)  [ok, unchanged].
//   prologue: stage h0..h4, vmcnt(6) confirms h0,h1.  Tail X-waits: 6 (u=U-3, stages
//     B(U-1) last), 2 (u=U-2: newest1=B(U-1) -> confirms B(U-2)), 0 (u=U-1).
// LDS swizzle (round-2, verified: conflicts 5.1M->0.39M): phys kgroup = logical ^ f(row),
//   f(row)=(row>>1)&3; pre-swizzled GLOBAL source + swizzled ds_read (rule #21).
template <bool BF16_OUT, bool EXPOUT>
__device__ __forceinline__ void gemm8_core(
    const u16* __restrict__ A, const u16* __restrict__ B, void* __restrict__ Cv,
    int K, int lda, int ldb, int ldc,
    long tile_m, long tile_n, long cbase,
    const float* __restrict__ bias_col, const float* __restrict__ bias_row,
    float scale, bool rope, float* __restrict__ rowsum, u16* smem)
{
    const int tid  = threadIdx.x;
    const int lane = tid & 63;
    const int wave = tid >> 6;
    const int wm2  = (wave >> 2) * 128;     // wave M offset (0/128)
    const int wn2  = (wave & 3) * 64;       // wave N offset (0/64/128/192)
    const int fm   = lane & 15;
    const int fks  = (((lane >> 4) ^ ((lane >> 1) & 3))) * 8;  // conflict-free k-group read

    // staging: 512 thr x 16B = 8KB per issue; half-tile = 2 issues (rows 0-127, 128-255)
    const int srow = tid >> 2;                            // 0..127
    const int kgl  = ((tid & 3) ^ ((tid >> 3) & 3)) * 8;  // pre-swizzled source k-group
    const u16* Asrc = A + (tile_m + srow) * (long)lda + kgl;
    const u16* Bsrc = B + (tile_n + srow) * (long)ldb + kgl;
    u16* dst0 = smem + tid * 8;                           // linear LDS dest (gload_lds rule)

    const int U = K >> 5;                                 // #k-substeps (>= 8 here)

    floatx4 acc[8][4] = {};
    short8 bf[4];

    auto stageA = [&](int v) {
        u16* d = dst0 + ((2 * v) & 7) * 8192;
        const u16* s = Asrc + v * 32;
        async_cp16(s, d);
        async_cp16(s + 128 * (long)lda, d + 4096);
    };
    auto stageB = [&](int v) {
        u16* d = dst0 + ((2 * v + 1) & 7) * 8192;
        const u16* s = Bsrc + v * 32;
        async_cp16(s, d);
        async_cp16(s + 128 * (long)ldb, d + 4096);
    };

    auto phase_pair = [&](int u, int vmx, bool stb, bool sta)
        __attribute__((always_inline))
    {
        const u16* Ap = smem + ((2 * u) & 7) * 8192;
        const u16* Bp = smem + ((2 * u + 1) & 7) * 8192;
        short8 af[4];
        // ---- phase X: M-half 0, full N, substep u
        #pragma unroll
        for (int i = 0; i < 4; ++i)
            af[i] = *reinterpret_cast<const short8*>(&Ap[(wm2 + i * 16 + fm) * 32 + fks]);
        #pragma unroll
        for (int j = 0; j < 4; ++j)
            bf[j] = *reinterpret_cast<const short8*>(&Bp[(wn2 + j * 16 + fm) * 32 + fks]);
        if (stb) stageB(u + 2);
        vmwait(vmx);
        barrier_raw();
        __builtin_amdgcn_sched_barrier(0);
        __builtin_amdgcn_s_setprio(1);
        #pragma unroll
        for (int i = 0; i < 4; ++i)
            #pragma unroll
            for (int j = 0; j < 4; ++j)
                acc[i][j] = __builtin_amdgcn_mfma_f32_16x16x32_bf16(af[i], bf[j], acc[i][j], 0, 0, 0);
        __builtin_amdgcn_s_setprio(0);
        __builtin_amdgcn_sched_barrier(0);
        barrier_raw();
        // ---- phase Y: M-half 1, reuse bf (no vmcnt: A(u) confirmed at X's wait)
        #pragma unroll
        for (int i = 0; i < 4; ++i)
            af[i] = *reinterpret_cast<const short8*>(&Ap[(wm2 + 64 + i * 16 + fm) * 32 + fks]);
        if (sta) stageA(u + 3);
        barrier_raw();
        __builtin_amdgcn_sched_barrier(0);
        __builtin_amdgcn_s_setprio(1);
        #pragma unroll
        for (int i = 0; i < 4; ++i)
            #pragma unroll
            for (int j = 0; j < 4; ++j)
                acc[4 + i][j] = __builtin_amdgcn_mfma_f32_16x16x32_bf16(af[i], bf[j], acc[4 + i][j], 0, 0, 0);
        __builtin_amdgcn_s_setprio(0);
        __builtin_amdgcn_sched_barrier(0);
        barrier_raw();
    };

    // prologue: h0..h4 = A0,B0,A1,B1,A2 ; vmcnt(6) confirms A0,B0
    stageA(0); stageB(0); stageA(1); stageB(1); stageA(2);
    vmwait(6);
    barrier_raw();

    for (int u = 0; u + 3 < U; ++u)
        phase_pair(u, 6, true, true);
    phase_pair(U - 3, 6, true,  false);   // X stages B(U-1), last stage
    phase_pair(U - 2, 2, false, false);   // newest1 = B(U-1) -> confirms B(U-2)
    phase_pair(U - 1, 0, false, false);

    // ---------------- epilogue (per-wave LDS transpose -> vectorized stores; proven code)
    // Bank audit: write stride 68 f32 -> 2-way (free); read float4 2-way (free).
    const int q4  = lane >> 4;
    const int c16 = lane & 15;
    float* smemf  = (float*)smem;
    float* myeps  = smemf + wave * (16 * 68);
    const long n0 = tile_n + wn2 + c16 * 4;

    float4 bc4 = make_float4(0.f, 0.f, 0.f, 0.f);
    if (bias_col) bc4 = *reinterpret_cast<const float4*>(bias_col + n0);

    float inv0 = 0.f, inv1 = 0.f;
    if (rope) {
        int p0 = (int)(n0 >> 1);
        inv0 = __expf((float)(p0 & 511)       * -1.79889463e-2f);
        inv1 = __expf((float)((p0 + 1) & 511) * -1.79889463e-2f);
    }

    #pragma unroll
    for (int i = 0; i < 8; ++i) {
        #pragma unroll
        for (int j = 0; j < 4; ++j)
            #pragma unroll
            for (int r = 0; r < 4; ++r)
                myeps[(q4 * 4 + r) * 68 + j * 16 + c16] = acc[i][j][r];
        __syncthreads();
        #pragma unroll
        for (int p = 0; p < 4; ++p) {
            int lrow = p * 4 + q4;
            long m = tile_m + wm2 + i * 16 + lrow;
            float4 v = *reinterpret_cast<const float4*>(&myeps[lrow * 68 + c16 * 4]);
            v.x = v.x * scale + bc4.x;
            v.y = v.y * scale + bc4.y;
            v.z = v.z * scale + bc4.z;
            v.w = v.w * scale + bc4.w;
            if (bias_row) {
                float br = bias_row[m];
                v.x += br; v.y += br; v.z += br; v.w += br;
            }
            if (rope) {
                int s = (int)(m & 2047);
                float a0 = (float)s * inv0, a1 = (float)s * inv1;
                float sn0 = __sinf(a0), cs0 = __cosf(a0);
                float sn1 = __sinf(a1), cs1 = __cosf(a1);
                float x0 = v.x, x1 = v.y, x2 = v.z, x3 = v.w;
                v.x = x0 * cs0 - x1 * sn0;
                v.y = x0 * sn0 + x1 * cs0;
                v.z = x2 * cs1 - x3 * sn1;
                v.w = x2 * sn1 + x3 * cs1;
            }
            if constexpr (EXPOUT) {
                v.x = __expf(v.x); v.y = __expf(v.y);
                v.z = __expf(v.z); v.w = __expf(v.w);
                float s4 = v.x + v.y + v.z + v.w;
                s4 += __shfl_xor(s4, 1);
                s4 += __shfl_xor(s4, 2);
                s4 += __shfl_xor(s4, 4);
                s4 += __shfl_xor(s4, 8);
                if (c16 == 0) atomicAdd(&rowsum[m], s4);
            }
            long off = cbase + m * (long)ldc + n0;
            if constexpr (BF16_OUT) {
                uint2 o;
                o.x = (u32)f2bf(v.x) | ((u32)f2bf(v.y) << 16);
                o.y = (u32)f2bf(v.z) | ((u32)f2bf(v.w) << 16);
                *reinterpret_cast<uint2*>((u16*)Cv + off) = o;
            } else {
                *reinterpret_cast<float4*>((float*)Cv + off) = v;
            }
        }
        __syncthreads();
    }
}

// fused G1 (QK-proj + RoPE, 256 blocks) + G2 (V^T proj, 128 blocks): 384 blocks x 512 thr
// NOTE: 1 block/CU => 384 jobs = 256-round + 128-round tail (~25% idle); candidate
// restructure (split G2 to 2-phase 128^2 core) deferred — single-variable discipline.
__global__ __launch_bounds__(512, 2)
void gemm8_fused12(const u16* __restrict__ xb, const u16* __restrict__ wqk,
                   const u16* __restrict__ wv, u16* __restrict__ QK, u16* __restrict__ VT,
                   const float* __restrict__ bqk, const float* __restrict__ wvb)
{
    u32 id = blockIdx.x;
    id = (id & 7u) * 48u + (id >> 3);          // XCD-contiguous remap (384 % 8 == 0)
    __shared__ alignas(16) u16 smem[65536];    // 128 KiB ring
    if (id < 256u) {                           // G1: M=8192, N=2048, K=1024
        u32 bx = id & 7u, by = id >> 3;
        gemm8_core<true, false>(xb, wqk, QK, 1024, 1024, 1024, 2048,
                                (long)by * 256, (long)bx * 256, 0L,
                                bqk, nullptr, 1.0f, true, nullptr, smem);
    } else {                                   // G2: per-batch M=1024, N=2048, K=1024
        u32 r = id - 256u;
        u32 bz = r >> 5, q = r & 31u, bx = q & 7u, by = q >> 3;
        gemm8_core<true, false>(wv, xb + (long)bz * 2048 * 1024, VT,
                                1024, 1024, 1024, 2048,
                                (long)by * 256, (long)bx * 256, (long)bz * 1024 * 2048,
                                nullptr, wvb, 1.0f, false, nullptr, smem);
    }
}

// G3: P_unnorm[b] = exp(Q[b] @ K[b]^T / 32) -> bf16, rowsum accumulated.  256 blocks (1/CU)
__global__ __launch_bounds__(512, 2)
void gemm8_qkt(const u16* __restrict__ QK, u16* __restrict__ Pbuf,
               float* __restrict__ rsum)
{
    u32 id = blockIdx.x;
    id = (id & 7u) * 32u + (id >> 3);          // XCD-contiguous remap (256 % 8 == 0)
    u32 bz = id >> 6, q = id & 63u, bx = q & 7u, by = q >> 3;
    __shared__ alignas(16) u16 smem[65536];
    const u16* base = QK + (long)bz * 2048 * 2048;
    gemm8_core<true, true>(base, base + 1024, Pbuf, 1024, 2048, 2048, 2048,
                           (long)by * 256, (long)bx * 256, (long)bz * 2048 * 2048,
                           nullptr, nullptr, 0.03125f, false,
                           rsum + (long)bz * 2048, smem);
}

// ---------------------------------------------------------------- G5 core (unchanged, proven)
// 128x64 tile, BK=64 (two 32-panels), 256 threads, 4 waves (each 64x32). 24KB LDS.
template <bool BF16_OUT>
__device__ __forceinline__ void gemm_core_n64(
    const u16* __restrict__ A, const u16* __restrict__ B, void* __restrict__ Cv,
    int K, int lda, int ldb, int ldc,
    long tile_m, long tile_n, long cbase,
    float scale, const float* __restrict__ rowscale, u16* smem)
{
    u16* As = smem;                 // panels: +c*4096 (128x32 each)
    u16* Bs = smem + 8192;          // panels: +c*2048 (64x32 each)

    const int tid  = threadIdx.x;
    const int lane = tid & 63;
    const int wave = tid >> 6;
    const int wm = (wave >> 1) << 6;       // 0 / 64
    const int wn = (wave & 1) << 5;        // 0 / 32

    floatx4 acc[4][2] = {};

    const int srow = tid >> 2;
    const int skp  = (((tid & 3) ^ (srow & 3))) * 8;
    const u16* Ag = A + (tile_m + srow) * (long)lda + skp;
    const u16* Bg = B + (tile_n + srow) * (long)ldb + skp;
    u16* Asl = &As[tid * 8];
    u16* Bsl = &Bs[tid * 8];

    const int fm  = lane & 15;
    const int fks = (((lane >> 4) ^ (lane & 3))) * 8;

    for (int k0 = 0; k0 < K; k0 += 64) {
        async_cp16(Ag,                       Asl);
        async_cp16(Ag + 64 * (long)lda,      Asl + 64 * 32);
        async_cp16(Ag + 32,                  Asl + 4096);
        async_cp16(Ag + 32 + 64 * (long)lda, Asl + 4096 + 64 * 32);
        async_cp16(Bg,                       Bsl);
        async_cp16(Bg + 32,                  Bsl + 2048);
        Ag += 64; Bg += 64;
        __syncthreads();

        #pragma unroll
        for (int c = 0; c < 2; ++c) {
            const u16* Ap = As + c * 4096;
            const u16* Bp = Bs + c * 2048;
            short8 af[4], bfr[2];
            #pragma unroll
            for (int i = 0; i < 4; ++i)
                af[i] = *reinterpret_cast<const short8*>(&Ap[(wm + i * 16 + fm) * 32 + fks]);
            #pragma unroll
            for (int j = 0; j < 2; ++j)
                bfr[j] = *reinterpret_cast<const short8*>(&Bp[(wn + j * 16 + fm) * 32 + fks]);
            #pragma unroll
            for (int i = 0; i < 4; ++i)
                #pragma unroll
                for (int j = 0; j < 2; ++j)
                    acc[i][j] = __builtin_amdgcn_mfma_f32_16x16x32_bf16(af[i], bfr[j], acc[i][j], 0, 0, 0);
        }
        __syncthreads();
    }

    const int q4  = lane >> 4;
    const int c16 = lane & 15;
    float* smemf = (float*)smem;
    float* myeps = smemf + wave * (16 * 36);
    const long n0 = tile_n + wn + c16 * 2;

    #pragma unroll
    for (int i = 0; i < 4; ++i) {
        #pragma unroll
        for (int j = 0; j < 2; ++j)
            #pragma unroll
            for (int r = 0; r < 4; ++r)
                myeps[(q4 * 4 + r) * 36 + j * 16 + c16] = acc[i][j][r];
        __syncthreads();
        #pragma unroll
        for (int p = 0; p < 4; ++p) {
            int lrow = p * 4 + q4;
            long m = tile_m + wm + i * 16 + lrow;
            float2 v = *reinterpret_cast<const float2*>(&myeps[lrow * 36 + c16 * 2]);
            float sc = scale;
            if (rowscale) sc *= 1.0f / rowscale[m];
            v.x *= sc; v.y *= sc;
            long off = cbase + m * (long)ldc + n0;
            if constexpr (BF16_OUT) {
                *reinterpret_cast<u32*>((u16*)Cv + off) =
                    (u32)f2bf(v.x) | ((u32)f2bf(v.y) << 16);
            } else {
                *reinterpret_cast<float2*>((float*)Cv + off) = v;
            }
        }
        __syncthreads();
    }
}

template <bool BF16_OUT>
__global__ __launch_bounds__(256)
void gemm_nt_n64(const u16* __restrict__ A, const u16* __restrict__ B, void* __restrict__ Cv,
                 int K, int lda, int ldb, int ldc,
                 long sA, long sB, long sC, float scale,
                 const float* __restrict__ rowscale)
{
    const u32 gx = gridDim.x, gy = gridDim.y;
    u32 id = blockIdx.x + gx * (blockIdx.y + gy * blockIdx.z);
    const u32 G = gx * gy * gridDim.z;
    if ((G & 7u) == 0u) id = (id & 7u) * (G >> 3) + (id >> 3);
    const u32 bx = id % gx;
    const u32 t1 = id / gx;
    const u32 by = t1 % gy;
    const u32 bz = t1 / gy;

    __shared__ alignas(16) u16 smem[12288];  // 24576 B
    gemm_core_n64<BF16_OUT>(A + (long)bz * sA, B + (long)bz * sB, Cv,
                            K, lda, ldb, ldc,
                            (long)by * 128, (long)bx * 64, (long)bz * sC,
                            scale, rowscale ? rowscale + (long)bz * 2048 : nullptr, smem);
}

// ---------------------------------------------------------------- launch
extern "C" void kernel_launch(void* const* d_in, const int* in_sizes, int n_in,
                              void* d_out, int out_size, void* d_ws, size_t ws_size,
                              hipStream_t stream)
{
    const float* x   = (const float*)d_in[0];
    const float* wqw = (const float*)d_in[1];
    const float* wqb = (const float*)d_in[2];
    const float* wkw = (const float*)d_in[3];
    const float* wkb = (const float*)d_in[4];
    const float* wvw = (const float*)d_in[5];
    const float* wvb = (const float*)d_in[6];
    float* out = (float*)d_out;

    char* ws = (char*)d_ws;
    const size_t MB = 1ull << 20;
    u16*   Pbuf = (u16*)(ws + 64 * MB);      // 32MB [4][2048][2048] bf16 P_unnorm = exp(S)
    u16*   QK   = (u16*)(ws + 96 * MB);      // 32MB [8192][2048] bf16 (Q | K), RoPE applied
    u16*   VT   = (u16*)(ws + 128 * MB);     // 16MB [4][1024][2048] bf16 (V transposed)
    float* rsum = (float*)(ws + 144 * MB);   // 32KB [8192] f32 softmax row sums
    u16*   xb    = (u16*)(ws + 0);           // 16MB [8192][1024]
    u16*   wqk   = (u16*)(ws + 16 * MB);     //  4MB [2048][1024]
    u16*   wvbuf = (u16*)(ws + 20 * MB);     //  2MB [1024][1024]
    float* bqk   = (float*)(ws + 22 * MB);   //  8KB [2048]

    // 1. all dtype conversions + bias concat + rowsum zeroing
    cvt_all<<<dim3(11280), 256, 0, stream>>>(x, xb, wqw, wkw, wvw,
                                             wqk, wqk + 1024 * 1024, wvbuf,
                                             wqb, wkb, bqk, rsum);

    // 2. fused G1 + G2 on the 8-phase 256^2 core (once-per-substep vmcnt)
    gemm8_fused12<<<dim3(384), 512, 0, stream>>>(xb, wqk, wvbuf, QK, VT, bqk, wvb);

    // 3. G3 on the 8-phase core: exp(QK^T/32) -> bf16 + rowsum
    gemm8_qkt<<<dim3(256), 512, 0, stream>>>(QK, Pbuf, rsum);

    // 4. G5: out[b] = (P_unnorm[b] @ VT[b]^T) / rowsum   (proven n64 core)
    gemm_nt_n64<false><<<dim3(16, 16, 4), 256, 0, stream>>>(
        Pbuf, VT, out, 2048, 2048, 2048, 1024,
        2048L * 2048, 1024L * 2048, 2048L * 1024, 1.0f, rsum);

    (void)in_sizes; (void)n_in; (void)out_size; (void)ws_size;
}

// Round 4
// 250.200 us; speedup vs baseline: 1.0845x; 1.0500x over previous
//
#include <hip/hip_runtime.h>
#include <cstdint>

using u16 = unsigned short;
using u32 = unsigned int;

typedef __attribute__((ext_vector_type(8))) short short8;   // 8 bf16 (A/B frag)
typedef __attribute__((ext_vector_type(4))) float floatx4;  // C frag

__device__ __forceinline__ u16 f2bf(float f) {
    u32 u = __float_as_uint(f);
    u32 r = u + 0x7fffu + ((u >> 16) & 1u);   // round-to-nearest-even
    return (u16)(r >> 16);
}

// ---------------------------------------------------------------- converts (one dispatch)
// [0,8192): x->bf16 ; [8192,11264): 3 weight mats ; [11264,11272): bias concat ;
// [11272,11280): zero rowsum[8192]
__global__ void cvt_all(const float* __restrict__ x, u16* __restrict__ xb,
                        const float* __restrict__ w0, const float* __restrict__ w1,
                        const float* __restrict__ w2,
                        u16* __restrict__ o0, u16* __restrict__ o1, u16* __restrict__ o2,
                        const float* __restrict__ qb, const float* __restrict__ kb,
                        float* __restrict__ bqk, float* __restrict__ rowsum)
{
    int b = blockIdx.x;
    if (b >= 11272) {              // zero rowsum: 8 blocks x 256 x 4 floats
        long i = ((long)(b - 11272) * 256 + threadIdx.x) * 4;
        *reinterpret_cast<float4*>(rowsum + i) = make_float4(0.f, 0.f, 0.f, 0.f);
        return;
    }
    if (b >= 11264) {              // bias concat: 8 blocks x 256 = 2048
        int i = (b - 11264) * 256 + threadIdx.x;
        bqk[i] = (i < 1024) ? qb[i] : kb[i - 1024];
        return;
    }
    const float* src; u16* dst; long base;
    if (b < 8192) { src = x; dst = xb; base = (long)b; }
    else {
        int r = b - 8192, seg = r >> 10;
        if (seg == 0)      { src = w0; dst = o0; }
        else if (seg == 1) { src = w1; dst = o1; }
        else               { src = w2; dst = o2; }
        base = (long)(r & 1023);
    }
    long i = (base * 256 + threadIdx.x) * 4;
    float4 v = *reinterpret_cast<const float4*>(src + i);
    uint2 o;
    o.x = (u32)f2bf(v.x) | ((u32)f2bf(v.y) << 16);
    o.y = (u32)f2bf(v.z) | ((u32)f2bf(v.w) << 16);
    *reinterpret_cast<uint2*>(dst + i) = o;
}

// ---------------------------------------------------------------- helpers
__device__ __forceinline__ void async_cp16(const u16* g, u16* l) {
    __builtin_amdgcn_global_load_lds(
        (const __attribute__((address_space(1))) void*)g,
        (__attribute__((address_space(3))) void*)l, 16, 0, 0);
}

#define MEMFENCE asm volatile("" ::: "memory")
__device__ __forceinline__ void barrier_raw() {
    MEMFENCE; __builtin_amdgcn_s_barrier(); MEMFENCE;
}
__device__ __forceinline__ void vmwait(int n) {   // folds when n is a literal
    if      (n == 6) asm volatile("s_waitcnt vmcnt(6)" ::: "memory");
    else if (n == 4) asm volatile("s_waitcnt vmcnt(4)" ::: "memory");
    else if (n == 2) asm volatile("s_waitcnt vmcnt(2)" ::: "memory");
    else if (n == 0) asm volatile("s_waitcnt vmcnt(0)" ::: "memory");
}

// ---------------------------------------------------------------- 2-phase GEMM core (NT)
// PROVEN round-0 structure (70 us on fused12).  128x128 tile, BK=64 (two 32-wide panels),
// 256 threads, 4 waves (each 64x64).  CONVOY NOTE: co-resident blocks traverse K in the
// SAME order — lockstep panel fetches create L2 reuse.  XCD-contiguous remap outside.
// rowscale (round-4 addition, G5): epilogue multiplies row m by scale/rowscale[m]
// (softmax normalization, numerics identical to the old n64 core).  nullptr = unchanged.
template <bool BF16_OUT, bool EXPOUT>
__device__ __forceinline__ void gemm_core(
    const u16* __restrict__ A, const u16* __restrict__ B, void* __restrict__ Cv,
    int K, int lda, int ldb, int ldc,
    long tile_m, long tile_n, long cbase,
    const float* bias_col, const float* bias_row,
    float scale, bool rope, float* __restrict__ rowsum,
    const float* __restrict__ rowscale, u16* smem)
{
    u16* As = smem;                 // panels: As + p*4096 (128x32 u16 each)
    u16* Bs = smem + 8192;

    const int tid  = threadIdx.x;
    const int lane = tid & 63;
    const int wave = tid >> 6;
    const int wm = (wave >> 1) << 6;
    const int wn = (wave & 1) << 6;

    floatx4 acc[4][4] = {};

    const int srow = tid >> 2;
    const int skp  = (((tid & 3) ^ (srow & 3))) * 8;
    const u16* Ag = A + (tile_m + srow) * (long)lda + skp;
    const u16* Bg = B + (tile_n + srow) * (long)ldb + skp;
    u16* Asl = &As[tid * 8];
    u16* Bsl = &Bs[tid * 8];

    const int fm  = lane & 15;
    const int fks = (((lane >> 4) ^ (lane & 3))) * 8;   // swizzled k-offset

    for (int k0 = 0; k0 < K; k0 += 64) {
        async_cp16(Ag,                       Asl);
        async_cp16(Ag + 64 * (long)lda,      Asl + 64 * 32);
        async_cp16(Ag + 32,                  Asl + 4096);
        async_cp16(Ag + 32 + 64 * (long)lda, Asl + 4096 + 64 * 32);
        async_cp16(Bg,                       Bsl);
        async_cp16(Bg + 64 * (long)ldb,      Bsl + 64 * 32);
        async_cp16(Bg + 32,                  Bsl + 4096);
        async_cp16(Bg + 32 + 64 * (long)ldb, Bsl + 4096 + 64 * 32);
        Ag += 64; Bg += 64;
        __syncthreads();

        #pragma unroll
        for (int c = 0; c < 2; ++c) {
            const u16* Ap = As + c * 4096;
            const u16* Bp = Bs + c * 4096;
            short8 af[4], bfr[4];
            #pragma unroll
            for (int i = 0; i < 4; ++i)
                af[i] = *reinterpret_cast<const short8*>(&Ap[(wm + i * 16 + fm) * 32 + fks]);
            #pragma unroll
            for (int j = 0; j < 4; ++j)
                bfr[j] = *reinterpret_cast<const short8*>(&Bp[(wn + j * 16 + fm) * 32 + fks]);
            #pragma unroll
            for (int i = 0; i < 4; ++i)
                #pragma unroll
                for (int j = 0; j < 4; ++j)
                    acc[i][j] = __builtin_amdgcn_mfma_f32_16x16x32_bf16(af[i], bfr[j], acc[i][j], 0, 0, 0);
        }
        __syncthreads();
    }

    // epilogue: per-wave LDS transpose -> vectorized stores
    const int q4  = lane >> 4;
    const int c16 = lane & 15;
    float* smemf  = (float*)smem;
    float* myeps = smemf + wave * (16 * 68);
    const long n0 = tile_n + wn + c16 * 4;

    float4 bc4 = make_float4(0.f, 0.f, 0.f, 0.f);
    if (bias_col) bc4 = *reinterpret_cast<const float4*>(bias_col + n0);

    float inv0 = 0.f, inv1 = 0.f;
    if (rope) {
        int p0 = (int)(n0 >> 1);
        inv0 = __expf((float)(p0 & 511)       * -1.79889463e-2f);
        inv1 = __expf((float)((p0 + 1) & 511) * -1.79889463e-2f);
    }

    #pragma unroll
    for (int i = 0; i < 4; ++i) {
        #pragma unroll
        for (int j = 0; j < 4; ++j)
            #pragma unroll
            for (int r = 0; r < 4; ++r)
                myeps[(q4 * 4 + r) * 68 + j * 16 + c16] = acc[i][j][r];
        __syncthreads();
        #pragma unroll
        for (int p = 0; p < 4; ++p) {
            int lrow = p * 4 + q4;
            long m = tile_m + wm + i * 16 + lrow;
            float4 v = *reinterpret_cast<const float4*>(&myeps[lrow * 68 + c16 * 4]);
            float sc = scale;
            if (rowscale) sc *= 1.0f / rowscale[m];
            v.x = v.x * sc + bc4.x;
            v.y = v.y * sc + bc4.y;
            v.z = v.z * sc + bc4.z;
            v.w = v.w * sc + bc4.w;
            if (bias_row) {
                float br = bias_row[m];
                v.x += br; v.y += br; v.z += br; v.w += br;
            }
            if (rope) {
                int s = (int)(m & 2047);
                float a0 = (float)s * inv0, a1 = (float)s * inv1;
                float sn0 = __sinf(a0), cs0 = __cosf(a0);
                float sn1 = __sinf(a1), cs1 = __cosf(a1);
                float x0 = v.x, x1 = v.y, x2 = v.z, x3 = v.w;
                v.x = x0 * cs0 - x1 * sn0;
                v.y = x0 * sn0 + x1 * cs0;
                v.z = x2 * cs1 - x3 * sn1;
                v.w = x2 * sn1 + x3 * cs1;
            }
            if constexpr (EXPOUT) {
                v.x = __expf(v.x); v.y = __expf(v.y);
                v.z = __expf(v.z); v.w = __expf(v.w);
                float s4 = v.x + v.y + v.z + v.w;     // 4 cols of row m
                s4 += __shfl_xor(s4, 1);              // sum across the 16-lane
                s4 += __shfl_xor(s4, 2);              // group holding 64 cols
                s4 += __shfl_xor(s4, 4);
                s4 += __shfl_xor(s4, 8);
                if (c16 == 0) atomicAdd(&rowsum[m], s4);
            }
            long off = cbase + m * (long)ldc + n0;
            if constexpr (BF16_OUT) {
                uint2 o;
                o.x = (u32)f2bf(v.x) | ((u32)f2bf(v.y) << 16);
                o.y = (u32)f2bf(v.z) | ((u32)f2bf(v.w) << 16);
                *reinterpret_cast<uint2*>((u16*)Cv + off) = o;
            } else {
                *reinterpret_cast<float4*>((float*)Cv + off) = v;
            }
        }
        __syncthreads();
    }
}

// ---------------------------------------------------------------- 8-phase 256x256 core
// Kept ONLY for G3 (256-block grid = exactly 1 block/CU, zero tail): measured ~12.5 us
// better than the 2-phase G3 (round-over-round algebra r0 vs r3).  Per-block MFMA util
// ~33% (vs m201's 62%) — cause unresolved after 3 single-variable probes (swizzle fixed,
// conflicts 5.1M->0.39M, null; wait cadence halved, null).  Do not extend to other GEMMs.
template <bool BF16_OUT, bool EXPOUT>
__device__ __forceinline__ void gemm8_core(
    const u16* __restrict__ A, const u16* __restrict__ B, void* __restrict__ Cv,
    int K, int lda, int ldb, int ldc,
    long tile_m, long tile_n, long cbase,
    const float* __restrict__ bias_col, const float* __restrict__ bias_row,
    float scale, bool rope, float* __restrict__ rowsum, u16* smem)
{
    const int tid  = threadIdx.x;
    const int lane = tid & 63;
    const int wave = tid >> 6;
    const int wm2  = (wave >> 2) * 128;     // wave M offset (0/128)
    const int wn2  = (wave & 3) * 64;       // wave N offset (0/64/128/192)
    const int fm   = lane & 15;
    const int fks  = (((lane >> 4) ^ ((lane >> 1) & 3))) * 8;  // conflict-free k-group read

    const int srow = tid >> 2;                            // 0..127
    const int kgl  = ((tid & 3) ^ ((tid >> 3) & 3)) * 8;  // pre-swizzled source k-group
    const u16* Asrc = A + (tile_m + srow) * (long)lda + kgl;
    const u16* Bsrc = B + (tile_n + srow) * (long)ldb + kgl;
    u16* dst0 = smem + tid * 8;                           // linear LDS dest (gload_lds rule)

    const int U = K >> 5;                                 // #k-substeps (>= 8 here)

    floatx4 acc[8][4] = {};
    short8 bf[4];

    auto stageA = [&](int v) {
        u16* d = dst0 + ((2 * v) & 7) * 8192;
        const u16* s = Asrc + v * 32;
        async_cp16(s, d);
        async_cp16(s + 128 * (long)lda, d + 4096);
    };
    auto stageB = [&](int v) {
        u16* d = dst0 + ((2 * v + 1) & 7) * 8192;
        const u16* s = Bsrc + v * 32;
        async_cp16(s, d);
        async_cp16(s + 128 * (long)ldb, d + 4096);
    };

    auto phase_pair = [&](int u, int vmx, bool stb, bool sta)
        __attribute__((always_inline))
    {
        const u16* Ap = smem + ((2 * u) & 7) * 8192;
        const u16* Bp = smem + ((2 * u + 1) & 7) * 8192;
        short8 af[4];
        #pragma unroll
        for (int i = 0; i < 4; ++i)
            af[i] = *reinterpret_cast<const short8*>(&Ap[(wm2 + i * 16 + fm) * 32 + fks]);
        #pragma unroll
        for (int j = 0; j < 4; ++j)
            bf[j] = *reinterpret_cast<const short8*>(&Bp[(wn2 + j * 16 + fm) * 32 + fks]);
        if (stb) stageB(u + 2);
        vmwait(vmx);
        barrier_raw();
        __builtin_amdgcn_sched_barrier(0);
        __builtin_amdgcn_s_setprio(1);
        #pragma unroll
        for (int i = 0; i < 4; ++i)
            #pragma unroll
            for (int j = 0; j < 4; ++j)
                acc[i][j] = __builtin_amdgcn_mfma_f32_16x16x32_bf16(af[i], bf[j], acc[i][j], 0, 0, 0);
        __builtin_amdgcn_s_setprio(0);
        __builtin_amdgcn_sched_barrier(0);
        barrier_raw();
        #pragma unroll
        for (int i = 0; i < 4; ++i)
            af[i] = *reinterpret_cast<const short8*>(&Ap[(wm2 + 64 + i * 16 + fm) * 32 + fks]);
        if (sta) stageA(u + 3);
        barrier_raw();
        __builtin_amdgcn_sched_barrier(0);
        __builtin_amdgcn_s_setprio(1);
        #pragma unroll
        for (int i = 0; i < 4; ++i)
            #pragma unroll
            for (int j = 0; j < 4; ++j)
                acc[4 + i][j] = __builtin_amdgcn_mfma_f32_16x16x32_bf16(af[i], bf[j], acc[4 + i][j], 0, 0, 0);
        __builtin_amdgcn_s_setprio(0);
        __builtin_amdgcn_sched_barrier(0);
        barrier_raw();
    };

    // prologue: h0..h4 = A0,B0,A1,B1,A2 ; vmcnt(6) confirms A0,B0
    stageA(0); stageB(0); stageA(1); stageB(1); stageA(2);
    vmwait(6);
    barrier_raw();

    for (int u = 0; u + 3 < U; ++u)
        phase_pair(u, 6, true, true);
    phase_pair(U - 3, 6, true,  false);   // X stages B(U-1), last stage
    phase_pair(U - 2, 2, false, false);   // newest1 = B(U-1) -> confirms B(U-2)
    phase_pair(U - 1, 0, false, false);

    // epilogue (identical numerics to 2-phase core, 8 acc rows)
    const int q4  = lane >> 4;
    const int c16 = lane & 15;
    float* smemf  = (float*)smem;
    float* myeps  = smemf + wave * (16 * 68);
    const long n0 = tile_n + wn2 + c16 * 4;

    float4 bc4 = make_float4(0.f, 0.f, 0.f, 0.f);
    if (bias_col) bc4 = *reinterpret_cast<const float4*>(bias_col + n0);

    float inv0 = 0.f, inv1 = 0.f;
    if (rope) {
        int p0 = (int)(n0 >> 1);
        inv0 = __expf((float)(p0 & 511)       * -1.79889463e-2f);
        inv1 = __expf((float)((p0 + 1) & 511) * -1.79889463e-2f);
    }

    #pragma unroll
    for (int i = 0; i < 8; ++i) {
        #pragma unroll
        for (int j = 0; j < 4; ++j)
            #pragma unroll
            for (int r = 0; r < 4; ++r)
                myeps[(q4 * 4 + r) * 68 + j * 16 + c16] = acc[i][j][r];
        __syncthreads();
        #pragma unroll
        for (int p = 0; p < 4; ++p) {
            int lrow = p * 4 + q4;
            long m = tile_m + wm2 + i * 16 + lrow;
            float4 v = *reinterpret_cast<const float4*>(&myeps[lrow * 68 + c16 * 4]);
            v.x = v.x * scale + bc4.x;
            v.y = v.y * scale + bc4.y;
            v.z = v.z * scale + bc4.z;
            v.w = v.w * scale + bc4.w;
            if (bias_row) {
                float br = bias_row[m];
                v.x += br; v.y += br; v.z += br; v.w += br;
            }
            if (rope) {
                int s = (int)(m & 2047);
                float a0 = (float)s * inv0, a1 = (float)s * inv1;
                float sn0 = __sinf(a0), cs0 = __cosf(a0);
                float sn1 = __sinf(a1), cs1 = __cosf(a1);
                float x0 = v.x, x1 = v.y, x2 = v.z, x3 = v.w;
                v.x = x0 * cs0 - x1 * sn0;
                v.y = x0 * sn0 + x1 * cs0;
                v.z = x2 * cs1 - x3 * sn1;
                v.w = x2 * sn1 + x3 * cs1;
            }
            if constexpr (EXPOUT) {
                v.x = __expf(v.x); v.y = __expf(v.y);
                v.z = __expf(v.z); v.w = __expf(v.w);
                float s4 = v.x + v.y + v.z + v.w;
                s4 += __shfl_xor(s4, 1);
                s4 += __shfl_xor(s4, 2);
                s4 += __shfl_xor(s4, 4);
                s4 += __shfl_xor(s4, 8);
                if (c16 == 0) atomicAdd(&rowsum[m], s4);
            }
            long off = cbase + m * (long)ldc + n0;
            if constexpr (BF16_OUT) {
                uint2 o;
                o.x = (u32)f2bf(v.x) | ((u32)f2bf(v.y) << 16);
                o.y = (u32)f2bf(v.z) | ((u32)f2bf(v.w) << 16);
                *reinterpret_cast<uint2*>((u16*)Cv + off) = o;
            } else {
                *reinterpret_cast<float4*>((float*)Cv + off) = v;
            }
        }
        __syncthreads();
    }
}

// fused G1 (QK-proj + RoPE) and G2 (V^T proj): 1536 blocks  (round-0 proven, 70 us)
__global__ __launch_bounds__(256)
void gemm_fused12(const u16* __restrict__ xb, const u16* __restrict__ wqk,
                  const u16* __restrict__ wv, u16* __restrict__ QK, u16* __restrict__ VT,
                  const float* __restrict__ bqk, const float* __restrict__ wvb)
{
    u32 id = blockIdx.x;                       // 1536
    id = (id & 7u) * 192u + (id >> 3);         // XCD-contiguous remap
    __shared__ alignas(16) u16 smem[16384];
    if (id < 1024u) {
        u32 bx = id & 15u, by = id >> 4;
        gemm_core<true, false>(xb, wqk, QK, 1024, 1024, 1024, 2048,
                        (long)by * 128, (long)bx * 128, 0L,
                        bqk, nullptr, 1.0f, true, nullptr, nullptr, smem);
    } else {
        u32 r = id - 1024u;
        u32 bx = r & 15u, by = (r >> 4) & 7u, bz = r >> 7;
        gemm_core<true, false>(wv, xb + (long)bz * 2048 * 1024, VT,
                        1024, 1024, 1024, 2048,
                        (long)by * 128, (long)bx * 128, (long)bz * 1024 * 2048,
                        nullptr, wvb, 1.0f, false, nullptr, nullptr, smem);
    }
}

// G3: P_unnorm[b] = exp(Q[b] @ K[b]^T / 32) -> bf16, rowsum accumulated.  256 blocks (1/CU)
__global__ __launch_bounds__(512, 2)
void gemm8_qkt(const u16* __restrict__ QK, u16* __restrict__ Pbuf,
               float* __restrict__ rsum)
{
    u32 id = blockIdx.x;
    id = (id & 7u) * 32u + (id >> 3);          // XCD-contiguous remap (256 % 8 == 0)
    u32 bz = id >> 6, q = id & 63u, bx = q & 7u, by = q >> 3;
    __shared__ alignas(16) u16 smem[65536];
    const u16* base = QK + (long)bz * 2048 * 2048;
    gemm8_core<true, true>(base, base + 1024, Pbuf, 1024, 2048, 2048, 2048,
                           (long)by * 256, (long)bx * 256, (long)bz * 2048 * 2048,
                           nullptr, nullptr, 0.03125f, false,
                           rsum + (long)bz * 2048, smem);
}

// G5 wrapper on the 128x128 2-phase core (round-4 change: was 128x64 n64 core).
// Grid (8,16,4) = 512 blocks of 128^2, K=2048: halves A-side panel re-reads (8 N-blocks
// share an A-panel instead of 16) and doubles per-block MFMA density.
template <bool BF16_OUT, bool EXPOUT>
__global__ __launch_bounds__(256)
void gemm_nt(const u16* __restrict__ A, const u16* __restrict__ B, void* __restrict__ Cv,
             int K, int lda, int ldb, int ldc,
             long sA, long sB, long sC,
             const float* __restrict__ bias_col, const float* __restrict__ bias_row,
             float scale, float* __restrict__ rowsum, const float* __restrict__ rowscale)
{
    const u32 gx = gridDim.x, gy = gridDim.y;
    u32 id = blockIdx.x + gx * (blockIdx.y + gy * blockIdx.z);
    const u32 G = gx * gy * gridDim.z;
    if ((G & 7u) == 0u) id = (id & 7u) * (G >> 3) + (id >> 3);
    const u32 bx = id % gx;
    const u32 t1 = id / gx;
    const u32 by = t1 % gy;
    const u32 bz = t1 / gy;

    __shared__ alignas(16) u16 smem[16384];
    gemm_core<BF16_OUT, EXPOUT>(A + (long)bz * sA, B + (long)bz * sB, Cv,
                        K, lda, ldb, ldc,
                        (long)by * 128, (long)bx * 128, (long)bz * sC,
                        bias_col, bias_row, scale, false,
                        rowsum ? rowsum + (long)bz * 2048 : nullptr,
                        rowscale ? rowscale + (long)bz * 2048 : nullptr, smem);
}

// ---------------------------------------------------------------- launch
extern "C" void kernel_launch(void* const* d_in, const int* in_sizes, int n_in,
                              void* d_out, int out_size, void* d_ws, size_t ws_size,
                              hipStream_t stream)
{
    const float* x   = (const float*)d_in[0];
    const float* wqw = (const float*)d_in[1];
    const float* wqb = (const float*)d_in[2];
    const float* wkw = (const float*)d_in[3];
    const float* wkb = (const float*)d_in[4];
    const float* wvw = (const float*)d_in[5];
    const float* wvb = (const float*)d_in[6];
    float* out = (float*)d_out;

    char* ws = (char*)d_ws;
    const size_t MB = 1ull << 20;
    u16*   Pbuf = (u16*)(ws + 64 * MB);      // 32MB [4][2048][2048] bf16 P_unnorm = exp(S)
    u16*   QK   = (u16*)(ws + 96 * MB);      // 32MB [8192][2048] bf16 (Q | K), RoPE applied
    u16*   VT   = (u16*)(ws + 128 * MB);     // 16MB [4][1024][2048] bf16 (V transposed)
    float* rsum = (float*)(ws + 144 * MB);   // 32KB [8192] f32 softmax row sums
    u16*   xb    = (u16*)(ws + 0);           // 16MB [8192][1024]
    u16*   wqk   = (u16*)(ws + 16 * MB);     //  4MB [2048][1024]
    u16*   wvbuf = (u16*)(ws + 20 * MB);     //  2MB [1024][1024]
    float* bqk   = (float*)(ws + 22 * MB);   //  8KB [2048]

    // 1. all dtype conversions + bias concat + rowsum zeroing
    cvt_all<<<dim3(11280), 256, 0, stream>>>(x, xb, wqw, wkw, wvw,
                                             wqk, wqk + 1024 * 1024, wvbuf,
                                             wqb, wkb, bqk, rsum);

    // 2. fused G1 + G2 (round-0 proven 2-phase 128^2 core)
    gemm_fused12<<<dim3(1536), 256, 0, stream>>>(xb, wqk, wvbuf, QK, VT, bqk, wvb);

    // 3. G3 on the 8-phase core (256 blocks, zero tail — measured win, kept)
    gemm8_qkt<<<dim3(256), 512, 0, stream>>>(QK, Pbuf, rsum);

    // 4. G5: out[b] = (P_unnorm[b] @ VT[b]^T) / rowsum on the 128^2 core (512 blocks)
    gemm_nt<false, false><<<dim3(8, 16, 4), 256, 0, stream>>>(
        Pbuf, VT, out, 2048, 2048, 2048, 1024,
        2048L * 2048, 1024L * 2048, 2048L * 1024,
        nullptr, nullptr, 1.0f, nullptr, rsum);

    (void)in_sizes; (void)n_in; (void)out_size; (void)ws_size;
}

// Round 6
// 236.580 us; speedup vs baseline: 1.1470x; 1.0576x over previous
//
#include <hip/hip_runtime.h>
#include <cstdint>

using u16 = unsigned short;
using u32 = unsigned int;

typedef __attribute__((ext_vector_type(8))) short short8;   // 8 bf16 (A/B frag)
typedef __attribute__((ext_vector_type(4))) float floatx4;  // C frag

__device__ __forceinline__ u16 f2bf(float f) {
    u32 u = __float_as_uint(f);
    u32 r = u + 0x7fffu + ((u >> 16) & 1u);   // round-to-nearest-even
    return (u16)(r >> 16);
}

// ---------------------------------------------------------------- converts (one dispatch)
// [0,8192): x->bf16 ; [8192,11264): 3 weight mats ; [11264,11272): bias concat ;
// [11272,11280): zero rowsum[8192]
__global__ void cvt_all(const float* __restrict__ x, u16* __restrict__ xb,
                        const float* __restrict__ w0, const float* __restrict__ w1,
                        const float* __restrict__ w2,
                        u16* __restrict__ o0, u16* __restrict__ o1, u16* __restrict__ o2,
                        const float* __restrict__ qb, const float* __restrict__ kb,
                        float* __restrict__ bqk, float* __restrict__ rowsum)
{
    int b = blockIdx.x;
    if (b >= 11272) {              // zero rowsum: 8 blocks x 256 x 4 floats
        long i = ((long)(b - 11272) * 256 + threadIdx.x) * 4;
        *reinterpret_cast<float4*>(rowsum + i) = make_float4(0.f, 0.f, 0.f, 0.f);
        return;
    }
    if (b >= 11264) {              // bias concat: 8 blocks x 256 = 2048
        int i = (b - 11264) * 256 + threadIdx.x;
        bqk[i] = (i < 1024) ? qb[i] : kb[i - 1024];
        return;
    }
    const float* src; u16* dst; long base;
    if (b < 8192) { src = x; dst = xb; base = (long)b; }
    else {
        int r = b - 8192, seg = r >> 10;
        if (seg == 0)      { src = w0; dst = o0; }
        else if (seg == 1) { src = w1; dst = o1; }
        else               { src = w2; dst = o2; }
        base = (long)(r & 1023);
    }
    long i = (base * 256 + threadIdx.x) * 4;
    float4 v = *reinterpret_cast<const float4*>(src + i);
    uint2 o;
    o.x = (u32)f2bf(v.x) | ((u32)f2bf(v.y) << 16);
    o.y = (u32)f2bf(v.z) | ((u32)f2bf(v.w) << 16);
    *reinterpret_cast<uint2*>(dst + i) = o;
}

// ---------------------------------------------------------------- helpers
__device__ __forceinline__ void async_cp16(const u16* g, u16* l) {
    __builtin_amdgcn_global_load_lds(
        (const __attribute__((address_space(1))) void*)g,
        (__attribute__((address_space(3))) void*)l, 16, 0, 0);
}

#define MEMFENCE asm volatile("" ::: "memory")
__device__ __forceinline__ void barrier_raw() {
    MEMFENCE; __builtin_amdgcn_s_barrier(); MEMFENCE;
}
__device__ __forceinline__ void vmwait(int n) {   // folds when n is a literal
    if      (n == 6) asm volatile("s_waitcnt vmcnt(6)" ::: "memory");
    else if (n == 4) asm volatile("s_waitcnt vmcnt(4)" ::: "memory");
    else if (n == 2) asm volatile("s_waitcnt vmcnt(2)" ::: "memory");
    else if (n == 0) asm volatile("s_waitcnt vmcnt(0)" ::: "memory");
}

// ---------------------------------------------------------------- 2-phase GEMM core (NT)
// PROVEN round-0 structure.  128x128 tile, BK=64 (two 32-wide panels), 256 threads,
// 4 waves (each 64x64).  CONVOY NOTE: co-resident blocks traverse K in the SAME order —
// lockstep panel fetches create the L2 reuse.  XCD-contiguous remap outside.
// ROUND-5/6: callers declare __launch_bounds__(256, 4) — arch+acc regs were 84+64=148,
// past the 128 halving step -> only 2 blocks/CU resident (Occupancy 25.8%); m114 says
// the barrier-drain stall needs ~3+ co-resident blocks to hide.  Cap forces arch<=64.
// (Round-5 bench never ran — container infra failure; this is the clean resubmit.)
template <bool BF16_OUT, bool EXPOUT>
__device__ __forceinline__ void gemm_core(
    const u16* __restrict__ A, const u16* __restrict__ B, void* __restrict__ Cv,
    int K, int lda, int ldb, int ldc,
    long tile_m, long tile_n, long cbase,
    const float* bias_col, const float* bias_row,
    float scale, bool rope, float* __restrict__ rowsum,
    const float* __restrict__ rowscale, u16* smem)
{
    u16* As = smem;                 // panels: As + p*4096 (128x32 u16 each)
    u16* Bs = smem + 8192;

    const int tid  = threadIdx.x;
    const int lane = tid & 63;
    const int wave = tid >> 6;
    const int wm = (wave >> 1) << 6;
    const int wn = (wave & 1) << 6;

    floatx4 acc[4][4] = {};

    const int srow = tid >> 2;
    const int skp  = (((tid & 3) ^ (srow & 3))) * 8;
    const u16* Ag = A + (tile_m + srow) * (long)lda + skp;
    const u16* Bg = B + (tile_n + srow) * (long)ldb + skp;
    u16* Asl = &As[tid * 8];
    u16* Bsl = &Bs[tid * 8];

    const int fm  = lane & 15;
    const int fks = (((lane >> 4) ^ (lane & 3))) * 8;   // swizzled k-offset

    for (int k0 = 0; k0 < K; k0 += 64) {
        async_cp16(Ag,                       Asl);
        async_cp16(Ag + 64 * (long)lda,      Asl + 64 * 32);
        async_cp16(Ag + 32,                  Asl + 4096);
        async_cp16(Ag + 32 + 64 * (long)lda, Asl + 4096 + 64 * 32);
        async_cp16(Bg,                       Bsl);
        async_cp16(Bg + 64 * (long)ldb,      Bsl + 64 * 32);
        async_cp16(Bg + 32,                  Bsl + 4096);
        async_cp16(Bg + 32 + 64 * (long)ldb, Bsl + 4096 + 64 * 32);
        Ag += 64; Bg += 64;
        __syncthreads();

        #pragma unroll
        for (int c = 0; c < 2; ++c) {
            const u16* Ap = As + c * 4096;
            const u16* Bp = Bs + c * 4096;
            short8 af[4], bfr[4];
            #pragma unroll
            for (int i = 0; i < 4; ++i)
                af[i] = *reinterpret_cast<const short8*>(&Ap[(wm + i * 16 + fm) * 32 + fks]);
            #pragma unroll
            for (int j = 0; j < 4; ++j)
                bfr[j] = *reinterpret_cast<const short8*>(&Bp[(wn + j * 16 + fm) * 32 + fks]);
            #pragma unroll
            for (int i = 0; i < 4; ++i)
                #pragma unroll
                for (int j = 0; j < 4; ++j)
                    acc[i][j] = __builtin_amdgcn_mfma_f32_16x16x32_bf16(af[i], bfr[j], acc[i][j], 0, 0, 0);
        }
        __syncthreads();
    }

    // epilogue: per-wave LDS transpose -> vectorized stores
    const int q4  = lane >> 4;
    const int c16 = lane & 15;
    float* smemf  = (float*)smem;
    float* myeps = smemf + wave * (16 * 68);
    const long n0 = tile_n + wn + c16 * 4;

    float4 bc4 = make_float4(0.f, 0.f, 0.f, 0.f);
    if (bias_col) bc4 = *reinterpret_cast<const float4*>(bias_col + n0);

    float inv0 = 0.f, inv1 = 0.f;
    if (rope) {
        int p0 = (int)(n0 >> 1);
        inv0 = __expf((float)(p0 & 511)       * -1.79889463e-2f);
        inv1 = __expf((float)((p0 + 1) & 511) * -1.79889463e-2f);
    }

    #pragma unroll
    for (int i = 0; i < 4; ++i) {
        #pragma unroll
        for (int j = 0; j < 4; ++j)
            #pragma unroll
            for (int r = 0; r < 4; ++r)
                myeps[(q4 * 4 + r) * 68 + j * 16 + c16] = acc[i][j][r];
        __syncthreads();
        #pragma unroll
        for (int p = 0; p < 4; ++p) {
            int lrow = p * 4 + q4;
            long m = tile_m + wm + i * 16 + lrow;
            float4 v = *reinterpret_cast<const float4*>(&myeps[lrow * 68 + c16 * 4]);
            float sc = scale;
            if (rowscale) sc *= 1.0f / rowscale[m];
            v.x = v.x * sc + bc4.x;
            v.y = v.y * sc + bc4.y;
            v.z = v.z * sc + bc4.z;
            v.w = v.w * sc + bc4.w;
            if (bias_row) {
                float br = bias_row[m];
                v.x += br; v.y += br; v.z += br; v.w += br;
            }
            if (rope) {
                int s = (int)(m & 2047);
                float a0 = (float)s * inv0, a1 = (float)s * inv1;
                float sn0 = __sinf(a0), cs0 = __cosf(a0);
                float sn1 = __sinf(a1), cs1 = __cosf(a1);
                float x0 = v.x, x1 = v.y, x2 = v.z, x3 = v.w;
                v.x = x0 * cs0 - x1 * sn0;
                v.y = x0 * sn0 + x1 * cs0;
                v.z = x2 * cs1 - x3 * sn1;
                v.w = x2 * sn1 + x3 * cs1;
            }
            if constexpr (EXPOUT) {
                v.x = __expf(v.x); v.y = __expf(v.y);
                v.z = __expf(v.z); v.w = __expf(v.w);
                float s4 = v.x + v.y + v.z + v.w;     // 4 cols of row m
                s4 += __shfl_xor(s4, 1);              // sum across the 16-lane
                s4 += __shfl_xor(s4, 2);              // group holding 64 cols
                s4 += __shfl_xor(s4, 4);
                s4 += __shfl_xor(s4, 8);
                if (c16 == 0) atomicAdd(&rowsum[m], s4);
            }
            long off = cbase + m * (long)ldc + n0;
            if constexpr (BF16_OUT) {
                uint2 o;
                o.x = (u32)f2bf(v.x) | ((u32)f2bf(v.y) << 16);
                o.y = (u32)f2bf(v.z) | ((u32)f2bf(v.w) << 16);
                *reinterpret_cast<uint2*>((u16*)Cv + off) = o;
            } else {
                *reinterpret_cast<float4*>((float*)Cv + off) = v;
            }
        }
        __syncthreads();
    }
}

// ---------------------------------------------------------------- 8-phase 256x256 core
// Kept ONLY for G3 (256-block grid = exactly 1 block/CU, zero tail): measured ~12.5 us
// better than the 2-phase G3.  Per-block MFMA util ~33% — cause unresolved after 3
// single-variable probes.  Do not extend to other GEMMs.
template <bool BF16_OUT, bool EXPOUT>
__device__ __forceinline__ void gemm8_core(
    const u16* __restrict__ A, const u16* __restrict__ B, void* __restrict__ Cv,
    int K, int lda, int ldb, int ldc,
    long tile_m, long tile_n, long cbase,
    const float* __restrict__ bias_col, const float* __restrict__ bias_row,
    float scale, bool rope, float* __restrict__ rowsum, u16* smem)
{
    const int tid  = threadIdx.x;
    const int lane = tid & 63;
    const int wave = tid >> 6;
    const int wm2  = (wave >> 2) * 128;     // wave M offset (0/128)
    const int wn2  = (wave & 3) * 64;       // wave N offset (0/64/128/192)
    const int fm   = lane & 15;
    const int fks  = (((lane >> 4) ^ ((lane >> 1) & 3))) * 8;  // conflict-free k-group read

    const int srow = tid >> 2;                            // 0..127
    const int kgl  = ((tid & 3) ^ ((tid >> 3) & 3)) * 8;  // pre-swizzled source k-group
    const u16* Asrc = A + (tile_m + srow) * (long)lda + kgl;
    const u16* Bsrc = B + (tile_n + srow) * (long)ldb + kgl;
    u16* dst0 = smem + tid * 8;                           // linear LDS dest (gload_lds rule)

    const int U = K >> 5;                                 // #k-substeps (>= 8 here)

    floatx4 acc[8][4] = {};
    short8 bf[4];

    auto stageA = [&](int v) {
        u16* d = dst0 + ((2 * v) & 7) * 8192;
        const u16* s = Asrc + v * 32;
        async_cp16(s, d);
        async_cp16(s + 128 * (long)lda, d + 4096);
    };
    auto stageB = [&](int v) {
        u16* d = dst0 + ((2 * v + 1) & 7) * 8192;
        const u16* s = Bsrc + v * 32;
        async_cp16(s, d);
        async_cp16(s + 128 * (long)ldb, d + 4096);
    };

    auto phase_pair = [&](int u, int vmx, bool stb, bool sta)
        __attribute__((always_inline))
    {
        const u16* Ap = smem + ((2 * u) & 7) * 8192;
        const u16* Bp = smem + ((2 * u + 1) & 7) * 8192;
        short8 af[4];
        #pragma unroll
        for (int i = 0; i < 4; ++i)
            af[i] = *reinterpret_cast<const short8*>(&Ap[(wm2 + i * 16 + fm) * 32 + fks]);
        #pragma unroll
        for (int j = 0; j < 4; ++j)
            bf[j] = *reinterpret_cast<const short8*>(&Bp[(wn2 + j * 16 + fm) * 32 + fks]);
        if (stb) stageB(u + 2);
        vmwait(vmx);
        barrier_raw();
        __builtin_amdgcn_sched_barrier(0);
        __builtin_amdgcn_s_setprio(1);
        #pragma unroll
        for (int i = 0; i < 4; ++i)
            #pragma unroll
            for (int j = 0; j < 4; ++j)
                acc[i][j] = __builtin_amdgcn_mfma_f32_16x16x32_bf16(af[i], bf[j], acc[i][j], 0, 0, 0);
        __builtin_amdgcn_s_setprio(0);
        __builtin_amdgcn_sched_barrier(0);
        barrier_raw();
        #pragma unroll
        for (int i = 0; i < 4; ++i)
            af[i] = *reinterpret_cast<const short8*>(&Ap[(wm2 + 64 + i * 16 + fm) * 32 + fks]);
        if (sta) stageA(u + 3);
        barrier_raw();
        __builtin_amdgcn_sched_barrier(0);
        __builtin_amdgcn_s_setprio(1);
        #pragma unroll
        for (int i = 0; i < 4; ++i)
            #pragma unroll
            for (int j = 0; j < 4; ++j)
                acc[4 + i][j] = __builtin_amdgcn_mfma_f32_16x16x32_bf16(af[i], bf[j], acc[4 + i][j], 0, 0, 0);
        __builtin_amdgcn_s_setprio(0);
        __builtin_amdgcn_sched_barrier(0);
        barrier_raw();
    };

    // prologue: h0..h4 = A0,B0,A1,B1,A2 ; vmcnt(6) confirms A0,B0
    stageA(0); stageB(0); stageA(1); stageB(1); stageA(2);
    vmwait(6);
    barrier_raw();

    for (int u = 0; u + 3 < U; ++u)
        phase_pair(u, 6, true, true);
    phase_pair(U - 3, 6, true,  false);   // X stages B(U-1), last stage
    phase_pair(U - 2, 2, false, false);   // newest1 = B(U-1) -> confirms B(U-2)
    phase_pair(U - 1, 0, false, false);

    // epilogue (identical numerics to 2-phase core, 8 acc rows)
    const int q4  = lane >> 4;
    const int c16 = lane & 15;
    float* smemf  = (float*)smem;
    float* myeps  = smemf + wave * (16 * 68);
    const long n0 = tile_n + wn2 + c16 * 4;

    float4 bc4 = make_float4(0.f, 0.f, 0.f, 0.f);
    if (bias_col) bc4 = *reinterpret_cast<const float4*>(bias_col + n0);

    float inv0 = 0.f, inv1 = 0.f;
    if (rope) {
        int p0 = (int)(n0 >> 1);
        inv0 = __expf((float)(p0 & 511)       * -1.79889463e-2f);
        inv1 = __expf((float)((p0 + 1) & 511) * -1.79889463e-2f);
    }

    #pragma unroll
    for (int i = 0; i < 8; ++i) {
        #pragma unroll
        for (int j = 0; j < 4; ++j)
            #pragma unroll
            for (int r = 0; r < 4; ++r)
                myeps[(q4 * 4 + r) * 68 + j * 16 + c16] = acc[i][j][r];
        __syncthreads();
        #pragma unroll
        for (int p = 0; p < 4; ++p) {
            int lrow = p * 4 + q4;
            long m = tile_m + wm2 + i * 16 + lrow;
            float4 v = *reinterpret_cast<const float4*>(&myeps[lrow * 68 + c16 * 4]);
            v.x = v.x * scale + bc4.x;
            v.y = v.y * scale + bc4.y;
            v.z = v.z * scale + bc4.z;
            v.w = v.w * scale + bc4.w;
            if (bias_row) {
                float br = bias_row[m];
                v.x += br; v.y += br; v.z += br; v.w += br;
            }
            if (rope) {
                int s = (int)(m & 2047);
                float a0 = (float)s * inv0, a1 = (float)s * inv1;
                float sn0 = __sinf(a0), cs0 = __cosf(a0);
                float sn1 = __sinf(a1), cs1 = __cosf(a1);
                float x0 = v.x, x1 = v.y, x2 = v.z, x3 = v.w;
                v.x = x0 * cs0 - x1 * sn0;
                v.y = x0 * sn0 + x1 * cs0;
                v.z = x2 * cs1 - x3 * sn1;
                v.w = x2 * sn1 + x3 * cs1;
            }
            if constexpr (EXPOUT) {
                v.x = __expf(v.x); v.y = __expf(v.y);
                v.z = __expf(v.z); v.w = __expf(v.w);
                float s4 = v.x + v.y + v.z + v.w;
                s4 += __shfl_xor(s4, 1);
                s4 += __shfl_xor(s4, 2);
                s4 += __shfl_xor(s4, 4);
                s4 += __shfl_xor(s4, 8);
                if (c16 == 0) atomicAdd(&rowsum[m], s4);
            }
            long off = cbase + m * (long)ldc + n0;
            if constexpr (BF16_OUT) {
                uint2 o;
                o.x = (u32)f2bf(v.x) | ((u32)f2bf(v.y) << 16);
                o.y = (u32)f2bf(v.z) | ((u32)f2bf(v.w) << 16);
                *reinterpret_cast<uint2*>((u16*)Cv + off) = o;
            } else {
                *reinterpret_cast<float4*>((float*)Cv + off) = v;
            }
        }
        __syncthreads();
    }
}

// fused G1 (QK-proj + RoPE) and G2 (V^T proj): 1536 blocks
// __launch_bounds__(256, 4): force arch regs <=64 so 4 blocks/CU fit
// (was 84+64=148 -> 2 blocks/CU, Occupancy 25.8%).
__global__ __launch_bounds__(256, 4)
void gemm_fused12(const u16* __restrict__ xb, const u16* __restrict__ wqk,
                  const u16* __restrict__ wv, u16* __restrict__ QK, u16* __restrict__ VT,
                  const float* __restrict__ bqk, const float* __restrict__ wvb)
{
    u32 id = blockIdx.x;                       // 1536
    id = (id & 7u) * 192u + (id >> 3);         // XCD-contiguous remap
    __shared__ alignas(16) u16 smem[16384];
    if (id < 1024u) {
        u32 bx = id & 15u, by = id >> 4;
        gemm_core<true, false>(xb, wqk, QK, 1024, 1024, 1024, 2048,
                        (long)by * 128, (long)bx * 128, 0L,
                        bqk, nullptr, 1.0f, true, nullptr, nullptr, smem);
    } else {
        u32 r = id - 1024u;
        u32 bx = r & 15u, by = (r >> 4) & 7u, bz = r >> 7;
        gemm_core<true, false>(wv, xb + (long)bz * 2048 * 1024, VT,
                        1024, 1024, 1024, 2048,
                        (long)by * 128, (long)bx * 128, (long)bz * 1024 * 2048,
                        nullptr, wvb, 1.0f, false, nullptr, nullptr, smem);
    }
}

// G3: P_unnorm[b] = exp(Q[b] @ K[b]^T / 32) -> bf16, rowsum accumulated.  256 blocks (1/CU)
__global__ __launch_bounds__(512, 2)
void gemm8_qkt(const u16* __restrict__ QK, u16* __restrict__ Pbuf,
               float* __restrict__ rsum)
{
    u32 id = blockIdx.x;
    id = (id & 7u) * 32u + (id >> 3);          // XCD-contiguous remap (256 % 8 == 0)
    u32 bz = id >> 6, q = id & 63u, bx = q & 7u, by = q >> 3;
    __shared__ alignas(16) u16 smem[65536];
    const u16* base = QK + (long)bz * 2048 * 2048;
    gemm8_core<true, true>(base, base + 1024, Pbuf, 1024, 2048, 2048, 2048,
                           (long)by * 256, (long)bx * 256, (long)bz * 2048 * 2048,
                           nullptr, nullptr, 0.03125f, false,
                           rsum + (long)bz * 2048, smem);
}

// G5 wrapper on the 128x128 2-phase core.  __launch_bounds__(256, 4) (see above).
template <bool BF16_OUT, bool EXPOUT>
__global__ __launch_bounds__(256, 4)
void gemm_nt(const u16* __restrict__ A, const u16* __restrict__ B, void* __restrict__ Cv,
             int K, int lda, int ldb, int ldc,
             long sA, long sB, long sC,
             const float* __restrict__ bias_col, const float* __restrict__ bias_row,
             float scale, float* __restrict__ rowsum, const float* __restrict__ rowscale)
{
    const u32 gx = gridDim.x, gy = gridDim.y;
    u32 id = blockIdx.x + gx * (blockIdx.y + gy * blockIdx.z);
    const u32 G = gx * gy * gridDim.z;
    if ((G & 7u) == 0u) id = (id & 7u) * (G >> 3) + (id >> 3);
    const u32 bx = id % gx;
    const u32 t1 = id / gx;
    const u32 by = t1 % gy;
    const u32 bz = t1 / gy;

    __shared__ alignas(16) u16 smem[16384];
    gemm_core<BF16_OUT, EXPOUT>(A + (long)bz * sA, B + (long)bz * sB, Cv,
                        K, lda, ldb, ldc,
                        (long)by * 128, (long)bx * 128, (long)bz * sC,
                        bias_col, bias_row, scale, false,
                        rowsum ? rowsum + (long)bz * 2048 : nullptr,
                        rowscale ? rowscale + (long)bz * 2048 : nullptr, smem);
}

// ---------------------------------------------------------------- launch
extern "C" void kernel_launch(void* const* d_in, const int* in_sizes, int n_in,
                              void* d_out, int out_size, void* d_ws, size_t ws_size,
                              hipStream_t stream)
{
    const float* x   = (const float*)d_in[0];
    const float* wqw = (const float*)d_in[1];
    const float* wqb = (const float*)d_in[2];
    const float* wkw = (const float*)d_in[3];
    const float* wkb = (const float*)d_in[4];
    const float* wvw = (const float*)d_in[5];
    const float* wvb = (const float*)d_in[6];
    float* out = (float*)d_out;

    char* ws = (char*)d_ws;
    const size_t MB = 1ull << 20;
    u16*   Pbuf = (u16*)(ws + 64 * MB);      // 32MB [4][2048][2048] bf16 P_unnorm = exp(S)
    u16*   QK   = (u16*)(ws + 96 * MB);      // 32MB [8192][2048] bf16 (Q | K), RoPE applied
    u16*   VT   = (u16*)(ws + 128 * MB);     // 16MB [4][1024][2048] bf16 (V transposed)
    float* rsum = (float*)(ws + 144 * MB);   // 32KB [8192] f32 softmax row sums
    u16*   xb    = (u16*)(ws + 0);           // 16MB [8192][1024]
    u16*   wqk   = (u16*)(ws + 16 * MB);     //  4MB [2048][1024]
    u16*   wvbuf = (u16*)(ws + 20 * MB);     //  2MB [1024][1024]
    float* bqk   = (float*)(ws + 22 * MB);   //  8KB [2048]

    // 1. all dtype conversions + bias concat + rowsum zeroing
    cvt_all<<<dim3(11280), 256, 0, stream>>>(x, xb, wqw, wkw, wvw,
                                             wqk, wqk + 1024 * 1024, wvbuf,
                                             wqb, wkb, bqk, rsum);

    // 2. fused G1 + G2 (2-phase 128^2 core, 4 blocks/CU target)
    gemm_fused12<<<dim3(1536), 256, 0, stream>>>(xb, wqk, wvbuf, QK, VT, bqk, wvb);

    // 3. G3 on the 8-phase core (256 blocks, zero tail — measured win, kept)
    gemm8_qkt<<<dim3(256), 512, 0, stream>>>(QK, Pbuf, rsum);

    // 4. G5: out[b] = (P_unnorm[b] @ VT[b]^T) / rowsum on the 128^2 core (512 blocks)
    gemm_nt<false, false><<<dim3(8, 16, 4), 256, 0, stream>>>(
        Pbuf, VT, out, 2048, 2048, 2048, 1024,
        2048L * 2048, 1024L * 2048, 2048L * 1024,
        nullptr, nullptr, 1.0f, nullptr, rsum);

    (void)in_sizes; (void)n_in; (void)out_size; (void)ws_size;
}